// Round 4
// baseline (568.245 us; speedup 1.0000x reference)
//
#include <hip/hip_runtime.h>
#include <stdint.h>

typedef unsigned short ushort_t;
typedef __attribute__((ext_vector_type(8))) short short8;   // 8 x bf16 bits
typedef __attribute__((ext_vector_type(4))) float float4v;  // MFMA C/D frag

static constexpr int N_=8192, C_=16;

// ---- ws layout (float offsets) ----
static constexpr long OFF_LOGITS = 0;                      // fp32 [131072][32]
static constexpr long OFF_PM  = 4194304;                   // [32][16][32]
static constexpr long OFF_PS  = 4210688;
static constexpr long OFF_M   = 4227072;                   // (unused)
static constexpr long OFF_INV = 4227584;                   // (unused)
static constexpr long OFF_SGL = 4228096;                   // (unused)
static constexpr long OFF_VGL = 4293632;                   // (unused)
static constexpr long OFF_KATT= 4342784;                   // bf16 [c][h][kt2][nt2][64][8]
static constexpr long OFF_VATT= 4408320;                   // bf16 [c][h][nt4][64][8]
static constexpr long OFF_WF  = 4473856;
// sub-offsets (floats) in OFF_WF region
static constexpr long WF_WHQ=0, WF_WHWP=1024, WF_KWH=2048, WF_KWS=3072, WF_KWV=23552,
  WF_KWSV=24576, WF_VWH=28672, WF_VWS=29696, WF_VWV=50176, WF_VWSV=51200,
  WF_B1=55296 /*bf16[6][10][64][8]*/, WF_BG=70656 /*bf16[4][2][64][8]*/,
  WF_BV=72704 /*bf16[2][64][8]*/;

// ---- d_out scratch byte offsets (all consumed before final outputs written) ----
static constexpr long VH_B   = 67108864;   // bf16 [131072*3][32]   (in out_v region, dead before k5)
static constexpr long AVN_B  = 92274688;   // bf16 [131072][64]     (in out_v region, dead before k5)
// k3 partials: fp32 [64][512][224] at VH_B (29.36 MB). vh_s/avn_s are dead by the
// time k3 runs (consumed by kB_gemm); k5's outv overwrites this region afterward.
static constexpr long PART_B = 67108864;
static constexpr long PART_ROWSZ = 224;            // floats per (a*16+c) row
static constexpr long PART_CHUNKSZ = 512*224;      // floats per chunk

__device__ __forceinline__ uint32_t f2bf(float f){
  uint32_t u = __float_as_uint(f);
  return (u + 0x7FFFu + ((u>>16)&1u)) >> 16;
}

// split fp32 into bf16 hi + bf16 lo (hi+lo represents f to ~2^-17 relative)
__device__ __forceinline__ void split_bf(float f, short& hi, short& lo){
  uint32_t u = __float_as_uint(f);
  uint32_t h = (u + 0x7FFFu + ((u>>16)&1u)) >> 16;
  hi = (short)h;
  float fh = __uint_as_float(h << 16);
  float r = f - fh;
  uint32_t u2 = __float_as_uint(r);
  lo = (short)((u2 + 0x7FFFu + ((u2>>16)&1u)) >> 16);
}

// B-fragment index helpers for mfma_f32_16x16x32_bf16:
// B[k][n] lives at lane = ((k&31)>>3)*16 + (n&15), j = k&7, tile nt = n>>4 (n in 0..31), kt = k>>5.
__device__ __forceinline__ long katt_idx(int c, int h, int k, int r){
  int kt=k>>5, kk=k&31, nt=r>>4;
  int lane=((kk>>3)<<4)|(r&15), j=kk&7;
  return ((((long)(c*4+h)*2+kt)*2+nt)*64+lane)*8+j;
}
__device__ __forceinline__ long vatt_idx(int c, int h, int r, int n2){
  int nt=n2>>4;
  int lane=((r>>3)<<4)|(n2&15), j=r&7;
  return (((long)(c*4+h)*4+nt)*64+lane)*8+j;
}

// ================= k0: weight prep (transposes + bf16 B-fragments) =================
__global__ void k0_prep(const float* __restrict__ wpwh, const float* __restrict__ wpws,
    const float* __restrict__ qwh, const float* __restrict__ qws, const float* __restrict__ qwv,
    const float* __restrict__ qwsv, const float* __restrict__ kwh, const float* __restrict__ kws,
    const float* __restrict__ kwv, const float* __restrict__ kwsv, const float* __restrict__ vwh,
    const float* __restrict__ vws, const float* __restrict__ vwv, const float* __restrict__ vwsv,
    float* __restrict__ wsf){
  int job=blockIdx.x, t=threadIdx.x;
  float* W = wsf + OFF_WF;
  auto tr=[&](const float* src, float* dst, int O, int J){
    for(int idx=t; idx<O*J; idx+=blockDim.x){int o=idx/J, j=idx-o*J; dst[j*O+o]=src[idx];}
  };
  switch(job){
    case 0: tr(qwh,  W+WF_WHQ, 32,32); break;
    case 1: tr(wpwh, W+WF_WHWP,32,32); break;
    case 2: tr(kwh,  W+WF_KWH, 32,32); break;
    case 3: tr(kws,  W+WF_KWS, 128,160); break;
    case 4: tr(kwv,  W+WF_KWV, 32,32); break;
    case 5: tr(kwsv, W+WF_KWSV,32,128); break;
    case 6: tr(vwh,  W+WF_VWH, 32,32); break;
    case 7: tr(vws,  W+WF_VWS, 128,160); break;
    case 8: tr(vwv,  W+WF_VWV, 32,32); break;
    case 9: tr(vwsv, W+WF_VWSV,32,128); break;
    case 10: { // B1[k 192][n 160]: k<128 -> s; 128..159 -> vn_q; 160..191 -> vn_wp
      ushort_t* dst=(ushort_t*)(W+WF_B1);
      for(int idx=t; idx<30720; idx+=blockDim.x){
        int j=idx&7, lane=(idx>>3)&63, tn=idx>>9, nt=tn%10, kt=tn/10;
        int k=kt*32+((lane>>4)<<3)+j, n=nt*16+(lane&15);
        float val;
        if(k<128)       val = (n<128)? qws[n*160+k]            : wpws[(n-128)*160+k];
        else if(k<160)  val = (n<128)? qws[n*160+k]            : 0.f;
        else            val = (n<128)? 0.f                     : wpws[(n-128)*160+(k-32)];
        dst[idx]=(ushort_t)f2bf(val);
      } } break;
    case 11: { // gate B: wsv^T [128][32]
      ushort_t* dst=(ushort_t*)(W+WF_BG);
      for(int idx=t; idx<4096; idx+=blockDim.x){
        int j=idx&7, lane=(idx>>3)&63, tn=idx>>9, nt=tn&1, kt=tn>>1;
        int k=kt*32+((lane>>4)<<3)+j, n=nt*16+(lane&15);
        dst[idx]=(ushort_t)f2bf(qwsv[n*128+k]);
      } } break;
    case 12: { // v_out B: wv^T [32][32]
      ushort_t* dst=(ushort_t*)(W+WF_BV);
      for(int idx=t; idx<1024; idx+=blockDim.x){
        int j=idx&7, lane=(idx>>3)&63, nt=idx>>9;
        int k=((lane>>4)<<3)+j, n=nt*16+(lane&15);
        dst[idx]=(ushort_t)f2bf(qwv[n*32+k]);
      } } break;
  }
}

// ================= kA: vh_q / vn_q / vn_wp (VALU, small) =================
__global__ __launch_bounds__(256) void kA_vn(const float* __restrict__ v,
    const float* __restrict__ wsf, ushort_t* __restrict__ vh_s, ushort_t* __restrict__ avn_s){
  __shared__ float whq[1024], whwp[1024];
  __shared__ float vb[4][96];
  int t=threadIdx.x, wave=t>>6, lane=t&63;
  for(int i=t;i<1024;i+=256){ whq[i]=wsf[OFF_WF+WF_WHQ+i]; whwp[i]=wsf[OFF_WF+WF_WHWP+i]; }
  __syncthreads();
  int h=lane&31, half=lane>>5;
  for(int it=0; it<32; it++){
    long inst = ((long)blockIdx.x*4 + wave)*32 + it;
    if(lane<48) ((float2*)vb[wave])[lane] = ((const float2*)v)[inst*48+lane];
    float d0=0,d1=0,d2=0;
    for(int i=half*16;i<half*16+16;i++){ float w=whq[i*32+h];
      d0+=vb[wave][3*i]*w; d1+=vb[wave][3*i+1]*w; d2+=vb[wave][3*i+2]*w; }
    d0+=__shfl_xor(d0,32,64); d1+=__shfl_xor(d1,32,64); d2+=__shfl_xor(d2,32,64);
    if(lane<32){
      float vn=sqrtf(fmaxf(d0*d0+d1*d1+d2*d2,1e-8f));
      avn_s[inst*64+h]=(ushort_t)f2bf(vn);
      vh_s[(inst*3+0)*32+h]=(ushort_t)f2bf(d0);
      vh_s[(inst*3+1)*32+h]=(ushort_t)f2bf(d1);
      vh_s[(inst*3+2)*32+h]=(ushort_t)f2bf(d2);
    }
    float e0=0,e1=0,e2=0;
    for(int i=half*16;i<half*16+16;i++){ float w=whwp[i*32+h];
      e0+=vb[wave][3*i]*w; e1+=vb[wave][3*i+1]*w; e2+=vb[wave][3*i+2]*w; }
    e0+=__shfl_xor(e0,32,64); e1+=__shfl_xor(e1,32,64); e2+=__shfl_xor(e2,32,64);
    if(lane<32){
      float vn=sqrtf(fmaxf(e0*e0+e1*e1+e2*e2,1e-8f));
      avn_s[inst*64+32+h]=(ushort_t)f2bf(vn);
    }
  }
}

// ================= kB: fused MFMA GEMM (q s_out + wp logits + gate + v_out) =================
// 128-thread blocks (2 waves). All LDS slices per-wave; no barriers needed.
// Epilogue scatter goes to LDS (qtile), then one coalesced 8 KB store per wave.
__global__ __launch_bounds__(128) void kB_gemm(const float* __restrict__ s,
    float* __restrict__ wsf,
    const float* __restrict__ qwsb, const float* __restrict__ wpwsb,
    const float* __restrict__ qwsvb,
    ushort_t* __restrict__ qatt, const ushort_t* __restrict__ vh_s,
    const ushort_t* __restrict__ avn_s){
  __shared__ ushort_t sigl[2][16*136];                  // sigmoid(s_out) bf16
  __shared__ float    gsigl[2][16*33];                  // sigmoid(gate) fp32
  __shared__ __align__(16) ushort_t qtile[2][16*264];   // q_att staging, rows padded to 264
  int t=threadIdx.x, wave=t>>6, lane=t&63;
  int l15=lane&15, lq=lane>>4;
  long m0 = ((long)blockIdx.x*2 + wave)*16;
  const short8* B1 = (const short8*)(wsf + OFF_WF + WF_B1);
  const short8* BG = (const short8*)(wsf + OFF_WF + WF_BG);
  const short8* BV = (const short8*)(wsf + OFF_WF + WF_BV);

  // ---- prefetch A-operands ----
  float4 f[4][2];
  #pragma unroll
  for(int kt=0;kt<4;kt++){
    const float* sp = s + (m0+l15)*128 + kt*32 + lq*8;
    f[kt][0]=*(const float4*)sp; f[kt][1]=*(const float4*)(sp+4);
  }
  short8 A4 = *(const short8*)&avn_s[(m0+l15)*64 + lq*8];
  short8 A5 = *(const short8*)&avn_s[(m0+l15)*64 + 32 + lq*8];
  short8 av0 = *(const short8*)&vh_s[(m0*3 + 0*16 + l15)*32 + lq*8];
  short8 av1 = *(const short8*)&vh_s[(m0*3 + 1*16 + l15)*32 + lq*8];
  short8 av2 = *(const short8*)&vh_s[(m0*3 + 2*16 + l15)*32 + lq*8];

  short8 A[6];
  #pragma unroll
  for(int kt=0;kt<4;kt++){
    short8 a;
    a[0]=(short)f2bf(f[kt][0].x); a[1]=(short)f2bf(f[kt][0].y);
    a[2]=(short)f2bf(f[kt][0].z); a[3]=(short)f2bf(f[kt][0].w);
    a[4]=(short)f2bf(f[kt][1].x); a[5]=(short)f2bf(f[kt][1].y);
    a[6]=(short)f2bf(f[kt][1].z); a[7]=(short)f2bf(f[kt][1].w);
    A[kt]=a;
  }
  A[4]=A4; A[5]=A5;

  float4v acc[10];
  #pragma unroll
  for(int i=0;i<10;i++) acc[i]=(float4v){0.f,0.f,0.f,0.f};
  #pragma unroll
  for(int kt=0;kt<6;kt++){
    #pragma unroll
    for(int nt=0;nt<10;nt++)
      acc[nt]=__builtin_amdgcn_mfma_f32_16x16x32_bf16(A[kt], B1[(kt*10+nt)*64+lane], acc[nt],0,0,0);
  }
  ushort_t* sl = sigl[wave]; float* gl = gsigl[wave];
  ushort_t* qt = qtile[wave];
  // zero the 8-pad slots (56..63) of each 64-block: one b128 per lane covers all
  {
    short8 z = {0,0,0,0,0,0,0,0};
    *(short8*)&qt[l15*264 + lq*64 + 56] = z;
  }
  // epilogue: silu -> qtile (LDS), sigmoid -> sigl; logits -> ws (fp32, coalesced)
  #pragma unroll
  for(int nt=0;nt<8;nt++){
    float b = qwsb[nt*16+l15];
    #pragma unroll
    for(int reg=0;reg<4;reg++){
      float x = acc[nt][reg] + b;
      float sg = 1.f/(1.f+__expf(-x));
      int row = lq*4+reg, col=nt*16+l15;
      qt[row*264 + (col>>5)*64 + (col&31)] = (ushort_t)f2bf(x*sg);
      sl[row*136+col] = (ushort_t)f2bf(sg);
    }
  }
  #pragma unroll
  for(int nt=8;nt<10;nt++){
    float b = wpwsb[(nt-8)*16+l15];
    #pragma unroll
    for(int reg=0;reg<4;reg++){
      long inst=m0+lq*4+reg;
      wsf[OFF_LOGITS + inst*32 + (nt-8)*16+l15] = acc[nt][reg]+b;
    }
  }
  // gate GEMM: sigmoid(s_out)[16x128] @ wsv^T[128x32]  (same-wave LDS)
  float4v g0=(float4v){0.f,0.f,0.f,0.f}, g1=g0;
  #pragma unroll
  for(int kt=0;kt<4;kt++){
    short8 a = *(const short8*)&sl[l15*136 + kt*32 + lq*8];
    g0=__builtin_amdgcn_mfma_f32_16x16x32_bf16(a, BG[(kt*2+0)*64+lane], g0,0,0,0);
    g1=__builtin_amdgcn_mfma_f32_16x16x32_bf16(a, BG[(kt*2+1)*64+lane], g1,0,0,0);
  }
  {
    float b0 = qwsvb[l15], b1 = qwsvb[16+l15];
    #pragma unroll
    for(int reg=0;reg<4;reg++){
      int row=lq*4+reg;
      gl[row*33 + l15]    = 1.f/(1.f+__expf(-(g0[reg]+b0)));
      gl[row*33 + 16+l15] = 1.f/(1.f+__expf(-(g1[reg]+b1)));
    }
  }
  // v_out GEMM: vh[(inst,d) x 32] @ wv^T[32x32], gated -> qtile cols 32..55
  #pragma unroll
  for(int tt=0;tt<3;tt++){
    short8 a = (tt==0)? av0 : (tt==1)? av1 : av2;
    float4v v0=(float4v){0.f,0.f,0.f,0.f}, v1=v0;
    v0=__builtin_amdgcn_mfma_f32_16x16x32_bf16(a, BV[0*64+lane], v0,0,0,0);
    v1=__builtin_amdgcn_mfma_f32_16x16x32_bf16(a, BV[1*64+lane], v1,0,0,0);
    #pragma unroll
    for(int nt2=0;nt2<2;nt2++){
      #pragma unroll
      for(int reg=0;reg<4;reg++){
        int lr = tt*16 + lq*4 + reg;
        int il = lr/3, d = lr - il*3;
        int o = nt2*16+l15;
        float val = (nt2? v1[reg] : v0[reg]) * gl[il*33+o];
        qt[il*264 + (o>>3)*64 + 32 + (o&7)*3 + d] = (ushort_t)f2bf(val);
      }
    }
  }
  // coalesced q_att store: wave's 16 insts -> 8 KB contiguous (1 KB per instruction)
  ushort_t* qdst = qatt + m0*256;
  #pragma unroll
  for(int ii=0; ii<8; ii++){
    int idx = ii*512 + lane*8;
    int row = idx>>8, off = idx&255;
    short8 val = *(const short8*)&qt[row*264+off];
    *(short8*)&qdst[idx] = val;
  }
}

// ================= k2a: softmax-over-N chunk stats =================
__global__ __launch_bounds__(256) void k2a_stats(float* __restrict__ ws){
  int c = blockIdx.x; int chunk = blockIdx.y;
  int t=threadIdx.x; int i=t>>5, a=t&31;
  const float* L = ws + OFF_LOGITS;
  float m=-1e30f, sum=0.f;
  for(int k2=0;k2<32;k2++){
    int n = chunk*256 + k2*8 + i;
    float x = L[((long)n*16 + c)*32 + a];
    float mn = fmaxf(m,x);
    sum = sum*__expf(m-mn) + __expf(x-mn);
    m = mn;
  }
  __shared__ float sm[8][32], ss[8][32];
  sm[i][a]=m; ss[i][a]=sum;
  __syncthreads();
  if(t<32){
    float M=sm[0][t], S=ss[0][t];
    for(int q=1;q<8;q++){
      float mq=sm[q][t], sq_=ss[q][t];
      float mn=fmaxf(M,mq); S=S*__expf(M-mn)+sq_*__expf(mq-mn); M=mn;
    }
    ws[OFF_PM + (chunk*16+c)*32 + t]=M;
    ws[OFF_PS + (chunk*16+c)*32 + t]=S;
  }
}

// ================= k3: s_global / v_global as MFMA GEMM, partials to scratch =================
// Merges the PM/PS chunk stats in-block (replaces k2b). Output tile [d x a] per c.
// Both operands split into bf16 hi+lo; 3 MFMAs per tile (hh + lh + hl) ~ fp32 grade.
template<int NMT, bool ISV>
__device__ __forceinline__ void k3_body(const float* __restrict__ X, int dx0, int pb0,
    const float* __restrict__ L, float M0, float M1, float I0, float I1,
    int c, int nb0, int l15, int lq, float* __restrict__ partc){
  constexpr int XP = ISV ? 96 : 128;
  float4v acc[NMT][2];
  #pragma unroll
  for(int mi=0;mi<NMT;mi++){
    acc[mi][0]=(float4v){0.f,0.f,0.f,0.f};
    acc[mi][1]=(float4v){0.f,0.f,0.f,0.f};
  }
  #pragma unroll
  for(int kt=0;kt<4;kt++){
    int nb = nb0 + kt*32 + lq*8;
    // B fragments: w = expf(L - M) * INV, hi/lo split, cols a=l15 (nt0) and 16+l15 (nt1)
    short8 bh0, bl0, bh1, bl1;
    #pragma unroll
    for(int j=0;j<8;j++){
      long ro = ((long)(nb+j)*16 + c)*32;
      float w0 = __expf(L[ro + l15]      - M0) * I0;
      float w1 = __expf(L[ro + 16 + l15] - M1) * I1;
      short h_, lo_;
      split_bf(w0, h_, lo_); bh0[j]=h_; bl0[j]=lo_;
      split_bf(w1, h_, lo_); bh1[j]=h_; bl1[j]=lo_;
    }
    #pragma unroll
    for(int mi=0;mi<NMT;mi++){
      short8 ah, al_;
      #pragma unroll
      for(int j=0;j<8;j++){
        float f = X[((long)(nb+j)*16 + c)*XP + dx0 + mi*16 + l15];
        short h_, lo_;
        split_bf(f, h_, lo_); ah[j]=h_; al_[j]=lo_;
      }
      acc[mi][0]=__builtin_amdgcn_mfma_f32_16x16x32_bf16(ah,  bh0, acc[mi][0],0,0,0);
      acc[mi][0]=__builtin_amdgcn_mfma_f32_16x16x32_bf16(al_, bh0, acc[mi][0],0,0,0);
      acc[mi][0]=__builtin_amdgcn_mfma_f32_16x16x32_bf16(ah,  bl0, acc[mi][0],0,0,0);
      acc[mi][1]=__builtin_amdgcn_mfma_f32_16x16x32_bf16(ah,  bh1, acc[mi][1],0,0,0);
      acc[mi][1]=__builtin_amdgcn_mfma_f32_16x16x32_bf16(al_, bh1, acc[mi][1],0,0,0);
      acc[mi][1]=__builtin_amdgcn_mfma_f32_16x16x32_bf16(ah,  bl1, acc[mi][1],0,0,0);
    }
  }
  // epilogue: float4 store partials. C/D: row (d) = lq*4+reg, col (a) = l15
  #pragma unroll
  for(int mi=0;mi<NMT;mi++){
    #pragma unroll
    for(int nt=0;nt<2;nt++){
      int a = nt*16 + l15;
      long row = (long)(a*16 + c);
      float4 val = make_float4(acc[mi][nt][0], acc[mi][nt][1], acc[mi][nt][2], acc[mi][nt][3]);
      *(float4*)&partc[row*PART_ROWSZ + pb0 + mi*16 + lq*4] = val;
    }
  }
}

__global__ __launch_bounds__(256) void k3_globals(const float* __restrict__ s,
    const float* __restrict__ v, const float* __restrict__ ws, float* __restrict__ part){
  int c = blockIdx.x & 15; int chunk = blockIdx.x >> 4;   // 64 chunks of 128 nodes
  int t=threadIdx.x, wave=t>>6, lane=t&63;
  int l15=lane&15, lq=lane>>4;
  const float* L = ws + OFF_LOGITS;
  __shared__ float sM[32], sI[32];
  if(t<32){
    int a=t;
    float M=-1e30f, S=0.f;
    #pragma unroll 4
    for(int ch=0; ch<32; ch++){
      float mq=ws[OFF_PM+(ch*16+c)*32+a], sq_=ws[OFF_PS+(ch*16+c)*32+a];
      float mn=fmaxf(M,mq); S=S*__expf(M-mn)+sq_*__expf(mq-mn); M=mn;
    }
    sM[a]=M; sI[a]=1.0f/S;
  }
  __syncthreads();
  float M0 = sM[l15], M1 = sM[16+l15];
  float I0 = sI[l15], I1 = sI[16+l15];
  int nb0 = chunk*128;
  float* partc = part + (long)chunk*PART_CHUNKSZ;
  // m-tile split across waves: w0: s d 0..63, w1: s d 64..127, w2: v 0..47, w3: v 48..95
  if(wave==0)      k3_body<4,false>(s, 0,  0,   L, M0,M1,I0,I1, c, nb0, l15, lq, partc);
  else if(wave==1) k3_body<4,false>(s, 64, 64,  L, M0,M1,I0,I1, c, nb0, l15, lq, partc);
  else if(wave==2) k3_body<3,true >(v, 0,  128, L, M0,M1,I0,I1, c, nb0, l15, lq, partc);
  else             k3_body<3,true >(v, 48, 176, L, M0,M1,I0,I1, c, nb0, l15, lq, partc);
}

// ================= k4: k / val GVPs -> K_att / V_att bf16 fragment buffers =================
// Also performs the 64-chunk partial reduction.
__global__ __launch_bounds__(64) void k4_kvgvp(float* __restrict__ wsf,
    const float* __restrict__ part,
    const float* __restrict__ k_wsb, const float* __restrict__ k_wsvb,
    const float* __restrict__ v_wsb, const float* __restrict__ v_wsvb){
  int a = blockIdx.x >> 4, c = blockIdx.x & 15;
  int lane = threadIdx.x;
  __shared__ __align__(16) float cat[160];
  __shared__ __align__(16) float vb2[96];
  __shared__ float vhb[96];
  __shared__ __align__(16) float sg[128];
  const float* W = wsf + OFF_WF;
  ushort_t* katt = (ushort_t*)(wsf + OFF_KATT);
  ushort_t* vatt = (ushort_t*)(wsf + OFF_VATT);
  long row = (long)a*16 + c;
  // reduce 64 chunk-partials for this (a,c) row: d 0..223 covered by lanes 0..55 (x4)
  {
    float4 accp = make_float4(0.f,0.f,0.f,0.f);
    if(lane<56){
      const float* pp = part + row*PART_ROWSZ + lane*4;
      #pragma unroll 8
      for(int ch=0; ch<64; ch++){
        float4 x = *(const float4*)(pp + (long)ch*PART_CHUNKSZ);
        accp.x+=x.x; accp.y+=x.y; accp.z+=x.z; accp.w+=x.w;
      }
    }
    if(lane<32)      *(float4*)&cat[lane*4]      = accp;
    else if(lane<56) *(float4*)&vb2[(lane-32)*4] = accp;
  }
  __syncthreads();
  if(a==0){ // zero pad slots k=56..63 (K) and n2=56..63 (V), all r, once per (c,h)
    for(int idx=lane; idx<1024; idx+=64){
      int h2=idx&3, kk=56+((idx>>2)&7), r=idx>>5;
      katt[katt_idx(c,h2,kk,r)]=0;
      vatt[vatt_idx(c,h2,r,kk)]=0;
    }
  }
  int h = lane&31, half = lane>>5;
  for(int p=0;p<2;p++){
    const float* wht  = W + (p? WF_VWH  : WF_KWH);
    const float* wst  = W + (p? WF_VWS  : WF_KWS);
    const float* wvt  = W + (p? WF_VWV  : WF_KWV);
    const float* wsvt = W + (p? WF_VWSV : WF_KWSV);
    const float* bs   = p? v_wsb : k_wsb;
    const float* bsv  = p? v_wsvb : k_wsvb;
    float d0=0.f,d1=0.f,d2=0.f;
    for(int i=half*16; i<half*16+16; i++){
      float w_=wht[i*32+h];
      d0+=vb2[3*i]*w_; d1+=vb2[3*i+1]*w_; d2+=vb2[3*i+2]*w_;
    }
    d0 += __shfl_xor(d0,32,64); d1 += __shfl_xor(d1,32,64); d2 += __shfl_xor(d2,32,64);
    if(lane<32){
      cat[128+h] = sqrtf(fmaxf(d0*d0+d1*d1+d2*d2, 1e-8f));
      vhb[3*h]=d0; vhb[3*h+1]=d1; vhb[3*h+2]=d2;
    }
    __syncthreads();
    float a0=bs[lane], a1=bs[lane+64];
    for(int j=0;j<160;j+=4){
      float4 c4=*((float4*)&cat[j]);
      a0 += c4.x*wst[j*128+lane]      + c4.y*wst[(j+1)*128+lane]
          + c4.z*wst[(j+2)*128+lane]  + c4.w*wst[(j+3)*128+lane];
      a1 += c4.x*wst[j*128+64+lane]   + c4.y*wst[(j+1)*128+64+lane]
          + c4.z*wst[(j+2)*128+64+lane]+ c4.w*wst[(j+3)*128+64+lane];
    }
    float sig0=1.f/(1.f+__expf(-a0)), sig1=1.f/(1.f+__expf(-a1));
    float silu0=a0*sig0, silu1=a1*sig1;
    sg[lane]=sig0; sg[lane+64]=sig1;
    // store s-part
    {
      int o=lane, hh2=o>>5, k=o&31;
      if(p==0) katt[katt_idx(c,hh2,k,a)] = (ushort_t)f2bf(silu0);
      else     vatt[vatt_idx(c,hh2,a,k)] = (ushort_t)f2bf(silu0);
    }
    {
      int o=lane+64, hh2=o>>5, k=o&31;
      if(p==0) katt[katt_idx(c,hh2,k,a)] = (ushort_t)f2bf(silu1);
      else     vatt[vatt_idx(c,hh2,a,k)] = (ushort_t)f2bf(silu1);
    }
    __syncthreads();
    float gacc=0.f;
    for(int o=half*64; o<half*64+64; o+=4){
      float4 s4_=*((float4*)&sg[o]);
      gacc += s4_.x*wsvt[o*32+h]+s4_.y*wsvt[(o+1)*32+h]+s4_.z*wsvt[(o+2)*32+h]+s4_.w*wsvt[(o+3)*32+h];
    }
    gacc += __shfl_xor(gacc,32,64);
    float sgate = 1.f/(1.f+__expf(-(gacc + bsv[h])));
    float e0=0.f,e1=0.f,e2=0.f;
    for(int hh=half*16; hh<half*16+16; hh++){
      float w_=wvt[hh*32+h];
      e0+=vhb[3*hh]*w_; e1+=vhb[3*hh+1]*w_; e2+=vhb[3*hh+2]*w_;
    }
    e0+=__shfl_xor(e0,32,64); e1+=__shfl_xor(e1,32,64); e2+=__shfl_xor(e2,32,64);
    if(lane<32){
      int hh2=lane>>3, oo=lane&7;
      float vals[3]={e0*sgate, e1*sgate, e2*sgate};
      #pragma unroll
      for(int d=0;d<3;d++){
        if(p==0) katt[katt_idx(c,hh2,32+oo*3+d,a)] = (ushort_t)f2bf(vals[d]);
        else     vatt[vatt_idx(c,hh2,a,32+oo*3+d)] = (ushort_t)f2bf(vals[d]);
      }
    }
    __syncthreads();
  }
}

// ================= k5: MFMA attention (reads q_att from d_out, overwrites outputs) ===========
// NOTE: no __syncthreads — al slices are strictly per-wave.
__global__ __launch_bounds__(256) void k5_attn(const float* __restrict__ wsf, float* out){
  __shared__ ushort_t al[4][4*16*40];   // alpha bf16, per wave, per h rows padded to 40
  int t=threadIdx.x, wave=t>>6, lane=t&63;
  int l15=lane&15, lq=lane>>4;
  int c=blockIdx.y;
  long n0 = ((long)blockIdx.x*4+wave)*16;
  const ushort_t* qatt = (const ushort_t*)out;    // ALIASES out: all reads precede writes
  const short8* KA = (const short8*)(wsf + OFF_KATT);
  const short8* VA = (const short8*)(wsf + OFF_VATT);
  const float scale = 0.15811388300841897f;  // 1/sqrt(40)
  float4v e[4][2];
  #pragma unroll
  for(int h=0;h<4;h++){ e[h][0]=(float4v){0.f,0.f,0.f,0.f}; e[h][1]=e[h][0]; }
  #pragma unroll
  for(int h=0;h<4;h++){
    #pragma unroll
    for(int kt=0;kt<2;kt++){
      short8 a = *(const short8*)&qatt[(((n0+l15)*16 + c)*4 + h)*64 + kt*32 + lq*8];
      e[h][0]=__builtin_amdgcn_mfma_f32_16x16x32_bf16(a, KA[(((c*4+h)*2+kt)*2+0)*64+lane], e[h][0],0,0,0);
      e[h][1]=__builtin_amdgcn_mfma_f32_16x16x32_bf16(a, KA[(((c*4+h)*2+kt)*2+1)*64+lane], e[h][1],0,0,0);
    }
  }
  ushort_t* alw = al[wave];
  #pragma unroll
  for(int h=0;h<4;h++){
    #pragma unroll
    for(int reg=0;reg<4;reg++){
      float a0=e[h][0][reg]*scale, a1=e[h][1][reg]*scale;
      float m=fmaxf(a0,a1);
      m=fmaxf(m,__shfl_xor(m,1,64)); m=fmaxf(m,__shfl_xor(m,2,64));
      m=fmaxf(m,__shfl_xor(m,4,64)); m=fmaxf(m,__shfl_xor(m,8,64));
      float p0=__expf(a0-m), p1=__expf(a1-m);
      float sum=p0+p1;
      sum+=__shfl_xor(sum,1,64); sum+=__shfl_xor(sum,2,64);
      sum+=__shfl_xor(sum,4,64); sum+=__shfl_xor(sum,8,64);
      float inv=1.f/sum;
      int row=lq*4+reg;
      alw[h*640 + row*40 + l15]      = (ushort_t)f2bf(p0*inv);
      alw[h*640 + row*40 + 16 + l15] = (ushort_t)f2bf(p1*inv);
    }
  }
  float* outv = out + 16777216;
  #pragma unroll
  for(int h=0;h<4;h++){
    short8 a = *(const short8*)&alw[h*640 + l15*40 + lq*8];
    #pragma unroll
    for(int nt=0;nt<4;nt++){
      float4v o_=(float4v){0.f,0.f,0.f,0.f};
      o_=__builtin_amdgcn_mfma_f32_16x16x32_bf16(a, VA[((c*4+h)*4+nt)*64+lane], o_,0,0,0);
      #pragma unroll
      for(int reg=0;reg<4;reg++){
        int n2=nt*16+l15, row=lq*4+reg;
        long inst=(n0+row)*16+c;
        float val=o_[reg];
        if(n2<32)      out[inst*128 + h*32+n2]=val;
        else if(n2<56) outv[inst*96 + h*24 + n2-32]=val;
      }
    }
  }
}

extern "C" void kernel_launch(void* const* d_in, const int* in_sizes, int n_in,
                              void* d_out, int out_size, void* d_ws, size_t ws_size,
                              hipStream_t stream){
  (void)in_sizes; (void)n_in; (void)out_size; (void)ws_size;
  const float* s = (const float*)d_in[0];
  const float* v = (const float*)d_in[1];
  float* wsf = (float*)d_ws;
  float* out = (float*)d_out;
  ushort_t* qatt  = (ushort_t*)d_out;
  ushort_t* vh_s  = (ushort_t*)((char*)d_out + VH_B);
  ushort_t* avn_s = (ushort_t*)((char*)d_out + AVN_B);
  float* part = (float*)((char*)d_out + PART_B);
  k0_prep<<<13,256,0,stream>>>(
      (const float*)d_in[2],(const float*)d_in[3],
      (const float*)d_in[5],(const float*)d_in[6],(const float*)d_in[8],(const float*)d_in[9],
      (const float*)d_in[11],(const float*)d_in[12],(const float*)d_in[14],(const float*)d_in[15],
      (const float*)d_in[17],(const float*)d_in[18],(const float*)d_in[20],(const float*)d_in[21], wsf);
  kA_vn<<<1024,256,0,stream>>>(v, wsf, vh_s, avn_s);
  kB_gemm<<<4096,128,0,stream>>>(s, wsf, (const float*)d_in[7], (const float*)d_in[4],
                                 (const float*)d_in[10], qatt, vh_s, avn_s);
  k2a_stats<<<dim3(16,32),256,0,stream>>>(wsf);
  k3_globals<<<1024,256,0,stream>>>(s, v, wsf, part);
  k4_kvgvp<<<512,64,0,stream>>>(wsf, part, (const float*)d_in[13], (const float*)d_in[16],
                                (const float*)d_in[19], (const float*)d_in[22]);
  k5_attn<<<dim3(128,16),256,0,stream>>>(wsf, out);
}

// Round 5
// 504.028 us; speedup vs baseline: 1.1274x; 1.1274x over previous
//
#include <hip/hip_runtime.h>
#include <stdint.h>

typedef unsigned short ushort_t;
typedef __attribute__((ext_vector_type(8))) short short8;   // 8 x bf16 bits
typedef __attribute__((ext_vector_type(4))) float float4v;  // MFMA C/D frag

static constexpr int N_=8192, C_=16;

// ---- ws layout (float offsets) ----
static constexpr long OFF_LOGITS = 0;                      // fp32 [131072][32]
static constexpr long OFF_PM  = 4194304;                   // [32][16][32]
static constexpr long OFF_PS  = 4210688;
static constexpr long OFF_M   = 4227072;                   // [16][32]
static constexpr long OFF_INV = 4227584;
static constexpr long OFF_SGL = 4228096;                   // (unused; layout stability)
static constexpr long OFF_VGL = 4293632;                   // (unused)
static constexpr long OFF_KATT= 4342784;                   // bf16 [c][h][kt2][nt2][64][8]
static constexpr long OFF_VATT= 4408320;                   // bf16 [c][h][nt4][64][8]
static constexpr long OFF_WF  = 4473856;
// sub-offsets (floats) in OFF_WF region
static constexpr long WF_WHQ=0, WF_WHWP=1024, WF_KWH=2048, WF_KWS=3072, WF_KWV=23552,
  WF_KWSV=24576, WF_VWH=28672, WF_VWS=29696, WF_VWV=50176, WF_VWSV=51200,
  WF_B1=55296 /*bf16[6][10][64][8]*/, WF_BG=70656 /*bf16[4][2][64][8]*/,
  WF_BV=72704 /*bf16[2][64][8]*/;

// ---- d_out scratch byte offsets (all consumed before final outputs written) ----
static constexpr long VH_B   = 67108864;   // bf16 [131072*3][32]   (in out_v region, dead before k5)
static constexpr long AVN_B  = 92274688;   // bf16 [131072][64]     (in out_v region, dead before k5)
// k3 partials: fp32 [64][512][224] at VH_B (29.36 MB). vh_s/avn_s are dead by the
// time k3 runs (consumed by kB_gemm); k5's outv overwrites this region afterward.
static constexpr long PART_B = 67108864;
static constexpr long PART_ROWSZ = 224;            // floats per (a*16+c) row
static constexpr long PART_CHUNKSZ = 512*224;      // floats per chunk

__device__ __forceinline__ uint32_t f2bf(float f){
  uint32_t u = __float_as_uint(f);
  return (u + 0x7FFFu + ((u>>16)&1u)) >> 16;
}

// split fp32 into bf16 hi + bf16 lo (hi+lo represents f to ~2^-17 relative)
__device__ __forceinline__ void split_bf(float f, short& hi, short& lo){
  uint32_t u = __float_as_uint(f);
  uint32_t h = (u + 0x7FFFu + ((u>>16)&1u)) >> 16;
  hi = (short)h;
  float fh = __uint_as_float(h << 16);
  float r = f - fh;
  uint32_t u2 = __float_as_uint(r);
  lo = (short)((u2 + 0x7FFFu + ((u2>>16)&1u)) >> 16);
}

// B-fragment index helpers for mfma_f32_16x16x32_bf16:
// B[k][n] lives at lane = ((k&31)>>3)*16 + (n&15), j = k&7, tile nt = n>>4 (n in 0..31), kt = k>>5.
__device__ __forceinline__ long katt_idx(int c, int h, int k, int r){
  int kt=k>>5, kk=k&31, nt=r>>4;
  int lane=((kk>>3)<<4)|(r&15), j=kk&7;
  return ((((long)(c*4+h)*2+kt)*2+nt)*64+lane)*8+j;
}
__device__ __forceinline__ long vatt_idx(int c, int h, int r, int n2){
  int nt=n2>>4;
  int lane=((r>>3)<<4)|(n2&15), j=r&7;
  return (((long)(c*4+h)*4+nt)*64+lane)*8+j;
}

// ================= k0: weight prep (transposes + bf16 B-fragments) =================
__global__ void k0_prep(const float* __restrict__ wpwh, const float* __restrict__ wpws,
    const float* __restrict__ qwh, const float* __restrict__ qws, const float* __restrict__ qwv,
    const float* __restrict__ qwsv, const float* __restrict__ kwh, const float* __restrict__ kws,
    const float* __restrict__ kwv, const float* __restrict__ kwsv, const float* __restrict__ vwh,
    const float* __restrict__ vws, const float* __restrict__ vwv, const float* __restrict__ vwsv,
    float* __restrict__ wsf){
  int job=blockIdx.x, t=threadIdx.x;
  float* W = wsf + OFF_WF;
  auto tr=[&](const float* src, float* dst, int O, int J){
    for(int idx=t; idx<O*J; idx+=blockDim.x){int o=idx/J, j=idx-o*J; dst[j*O+o]=src[idx];}
  };
  switch(job){
    case 0: tr(qwh,  W+WF_WHQ, 32,32); break;
    case 1: tr(wpwh, W+WF_WHWP,32,32); break;
    case 2: tr(kwh,  W+WF_KWH, 32,32); break;
    case 3: tr(kws,  W+WF_KWS, 128,160); break;
    case 4: tr(kwv,  W+WF_KWV, 32,32); break;
    case 5: tr(kwsv, W+WF_KWSV,32,128); break;
    case 6: tr(vwh,  W+WF_VWH, 32,32); break;
    case 7: tr(vws,  W+WF_VWS, 128,160); break;
    case 8: tr(vwv,  W+WF_VWV, 32,32); break;
    case 9: tr(vwsv, W+WF_VWSV,32,128); break;
    case 10: { // B1[k 192][n 160]: k<128 -> s; 128..159 -> vn_q; 160..191 -> vn_wp
      ushort_t* dst=(ushort_t*)(W+WF_B1);
      for(int idx=t; idx<30720; idx+=blockDim.x){
        int j=idx&7, lane=(idx>>3)&63, tn=idx>>9, nt=tn%10, kt=tn/10;
        int k=kt*32+((lane>>4)<<3)+j, n=nt*16+(lane&15);
        float val;
        if(k<128)       val = (n<128)? qws[n*160+k]            : wpws[(n-128)*160+k];
        else if(k<160)  val = (n<128)? qws[n*160+k]            : 0.f;
        else            val = (n<128)? 0.f                     : wpws[(n-128)*160+(k-32)];
        dst[idx]=(ushort_t)f2bf(val);
      } } break;
    case 11: { // gate B: wsv^T [128][32]
      ushort_t* dst=(ushort_t*)(W+WF_BG);
      for(int idx=t; idx<4096; idx+=blockDim.x){
        int j=idx&7, lane=(idx>>3)&63, tn=idx>>9, nt=tn&1, kt=tn>>1;
        int k=kt*32+((lane>>4)<<3)+j, n=nt*16+(lane&15);
        dst[idx]=(ushort_t)f2bf(qwsv[n*128+k]);
      } } break;
    case 12: { // v_out B: wv^T [32][32]
      ushort_t* dst=(ushort_t*)(W+WF_BV);
      for(int idx=t; idx<1024; idx+=blockDim.x){
        int j=idx&7, lane=(idx>>3)&63, nt=idx>>9;
        int k=((lane>>4)<<3)+j, n=nt*16+(lane&15);
        dst[idx]=(ushort_t)f2bf(qwv[n*32+k]);
      } } break;
  }
}

// ================= kA: vh_q / vn_q / vn_wp (VALU, small) =================
__global__ __launch_bounds__(256) void kA_vn(const float* __restrict__ v,
    const float* __restrict__ wsf, ushort_t* __restrict__ vh_s, ushort_t* __restrict__ avn_s){
  __shared__ float whq[1024], whwp[1024];
  __shared__ float vb[4][96];
  int t=threadIdx.x, wave=t>>6, lane=t&63;
  for(int i=t;i<1024;i+=256){ whq[i]=wsf[OFF_WF+WF_WHQ+i]; whwp[i]=wsf[OFF_WF+WF_WHWP+i]; }
  __syncthreads();
  int h=lane&31, half=lane>>5;
  for(int it=0; it<32; it++){
    long inst = ((long)blockIdx.x*4 + wave)*32 + it;
    if(lane<48) ((float2*)vb[wave])[lane] = ((const float2*)v)[inst*48+lane];
    float d0=0,d1=0,d2=0;
    for(int i=half*16;i<half*16+16;i++){ float w=whq[i*32+h];
      d0+=vb[wave][3*i]*w; d1+=vb[wave][3*i+1]*w; d2+=vb[wave][3*i+2]*w; }
    d0+=__shfl_xor(d0,32,64); d1+=__shfl_xor(d1,32,64); d2+=__shfl_xor(d2,32,64);
    if(lane<32){
      float vn=sqrtf(fmaxf(d0*d0+d1*d1+d2*d2,1e-8f));
      avn_s[inst*64+h]=(ushort_t)f2bf(vn);
      vh_s[(inst*3+0)*32+h]=(ushort_t)f2bf(d0);
      vh_s[(inst*3+1)*32+h]=(ushort_t)f2bf(d1);
      vh_s[(inst*3+2)*32+h]=(ushort_t)f2bf(d2);
    }
    float e0=0,e1=0,e2=0;
    for(int i=half*16;i<half*16+16;i++){ float w=whwp[i*32+h];
      e0+=vb[wave][3*i]*w; e1+=vb[wave][3*i+1]*w; e2+=vb[wave][3*i+2]*w; }
    e0+=__shfl_xor(e0,32,64); e1+=__shfl_xor(e1,32,64); e2+=__shfl_xor(e2,32,64);
    if(lane<32){
      float vn=sqrtf(fmaxf(e0*e0+e1*e1+e2*e2,1e-8f));
      avn_s[inst*64+32+h]=(ushort_t)f2bf(vn);
    }
  }
}

// ================= kB: fused MFMA GEMM (q s_out + wp logits + gate + v_out) =================
// R2 structure (best measured: 82 µs): 256-thr, on-the-fly A loads, scatter stores.
__global__ __launch_bounds__(256) void kB_gemm(const float* __restrict__ s,
    float* __restrict__ wsf,
    const float* __restrict__ qwsb, const float* __restrict__ wpwsb,
    const float* __restrict__ qwsvb,
    ushort_t* __restrict__ qatt, const ushort_t* __restrict__ vh_s,
    const ushort_t* __restrict__ avn_s){
  __shared__ ushort_t sigl[4][16*136];   // sigmoid(s_out) bf16, rows padded to 136
  __shared__ float    gsigl[4][16*33];   // sigmoid(gate) fp32
  int t=threadIdx.x, wave=t>>6, lane=t&63;
  int l15=lane&15, lq=lane>>4;
  long m0 = ((long)blockIdx.x*4 + wave)*16;
  const short8* B1 = (const short8*)(wsf + OFF_WF + WF_B1);
  const short8* BG = (const short8*)(wsf + OFF_WF + WF_BG);
  const short8* BV = (const short8*)(wsf + OFF_WF + WF_BV);
  // zero qatt pad cols 56..63 of each 64-block (k5 A-operand safety: pad*0 rows)
  {
    short8 z = {0,0,0,0,0,0,0,0};
    *(short8*)&qatt[((m0+l15)*4 + lq)*64 + 56] = z;
  }
  float4v acc[10];
  #pragma unroll
  for(int i=0;i<10;i++) acc[i]=(float4v){0.f,0.f,0.f,0.f};
  // K 0..127: s (fp32 -> bf16 on the fly)
  #pragma unroll
  for(int kt=0;kt<4;kt++){
    const float* sp = s + (m0+l15)*128 + kt*32 + lq*8;
    float4 f0=*(const float4*)sp, f1=*(const float4*)(sp+4);
    short8 a;
    a[0]=(short)f2bf(f0.x); a[1]=(short)f2bf(f0.y); a[2]=(short)f2bf(f0.z); a[3]=(short)f2bf(f0.w);
    a[4]=(short)f2bf(f1.x); a[5]=(short)f2bf(f1.y); a[6]=(short)f2bf(f1.z); a[7]=(short)f2bf(f1.w);
    #pragma unroll
    for(int nt=0;nt<10;nt++)
      acc[nt]=__builtin_amdgcn_mfma_f32_16x16x32_bf16(a, B1[(kt*10+nt)*64+lane], acc[nt],0,0,0);
  }
  // K 128..191: [vn_q | vn_wp]
  #pragma unroll
  for(int kt=4;kt<6;kt++){
    short8 a = *(const short8*)&avn_s[(m0+l15)*64 + (kt-4)*32 + lq*8];
    #pragma unroll
    for(int nt=0;nt<10;nt++)
      acc[nt]=__builtin_amdgcn_mfma_f32_16x16x32_bf16(a, B1[(kt*10+nt)*64+lane], acc[nt],0,0,0);
  }
  ushort_t* sl = sigl[wave]; float* gl = gsigl[wave];
  // epilogue: silu -> q_att (bf16), sigmoid -> LDS; logits -> ws (fp32)
  #pragma unroll
  for(int nt=0;nt<8;nt++){
    float b = qwsb[nt*16+l15];
    #pragma unroll
    for(int reg=0;reg<4;reg++){
      float x = acc[nt][reg] + b;
      float sg = 1.f/(1.f+__expf(-x));
      int row = lq*4+reg, col=nt*16+l15;
      long inst = m0+row;
      qatt[(inst*4 + (col>>5))*64 + (col&31)] = (ushort_t)f2bf(x*sg);
      sl[row*136+col] = (ushort_t)f2bf(sg);
    }
  }
  #pragma unroll
  for(int nt=8;nt<10;nt++){
    float b = wpwsb[(nt-8)*16+l15];
    #pragma unroll
    for(int reg=0;reg<4;reg++){
      long inst=m0+lq*4+reg;
      wsf[OFF_LOGITS + inst*32 + (nt-8)*16+l15] = acc[nt][reg]+b;
    }
  }
  __syncthreads();
  // gate GEMM: sigmoid(s_out)[16x128] @ wsv^T[128x32]
  float4v g0=(float4v){0.f,0.f,0.f,0.f}, g1=g0;
  #pragma unroll
  for(int kt=0;kt<4;kt++){
    short8 a = *(const short8*)&sl[l15*136 + kt*32 + lq*8];
    g0=__builtin_amdgcn_mfma_f32_16x16x32_bf16(a, BG[(kt*2+0)*64+lane], g0,0,0,0);
    g1=__builtin_amdgcn_mfma_f32_16x16x32_bf16(a, BG[(kt*2+1)*64+lane], g1,0,0,0);
  }
  {
    float b0 = qwsvb[l15], b1 = qwsvb[16+l15];
    #pragma unroll
    for(int reg=0;reg<4;reg++){
      int row=lq*4+reg;
      gl[row*33 + l15]    = 1.f/(1.f+__expf(-(g0[reg]+b0)));
      gl[row*33 + 16+l15] = 1.f/(1.f+__expf(-(g1[reg]+b1)));
    }
  }
  __syncthreads();
  // v_out GEMM: vh[(inst,d) x 32] @ wv^T[32x32], gated, -> q_att qv part (bf16)
  #pragma unroll
  for(int tt=0;tt<3;tt++){
    short8 a = *(const short8*)&vh_s[(m0*3 + tt*16 + l15)*32 + lq*8];
    float4v v0=(float4v){0.f,0.f,0.f,0.f}, v1=v0;
    v0=__builtin_amdgcn_mfma_f32_16x16x32_bf16(a, BV[0*64+lane], v0,0,0,0);
    v1=__builtin_amdgcn_mfma_f32_16x16x32_bf16(a, BV[1*64+lane], v1,0,0,0);
    #pragma unroll
    for(int nt2=0;nt2<2;nt2++){
      #pragma unroll
      for(int reg=0;reg<4;reg++){
        int lr = tt*16 + lq*4 + reg;
        int il = lr/3, d = lr - il*3;
        int o = nt2*16+l15;
        float val = (nt2? v1[reg] : v0[reg]) * gl[il*33+o];
        long inst = m0 + il;
        qatt[(inst*4 + (o>>3))*64 + 32 + (o&7)*3 + d] = (ushort_t)f2bf(val);
      }
    }
  }
}

// ================= k2a/k2b: softmax-over-N stats =================
__global__ __launch_bounds__(256) void k2a_stats(float* __restrict__ ws){
  int c = blockIdx.x; int chunk = blockIdx.y;
  int t=threadIdx.x; int i=t>>5, a=t&31;
  const float* L = ws + OFF_LOGITS;
  float m=-1e30f, sum=0.f;
  for(int k2=0;k2<32;k2++){
    int n = chunk*256 + k2*8 + i;
    float x = L[((long)n*16 + c)*32 + a];
    float mn = fmaxf(m,x);
    sum = sum*__expf(m-mn) + __expf(x-mn);
    m = mn;
  }
  __shared__ float sm[8][32], ss[8][32];
  sm[i][a]=m; ss[i][a]=sum;
  __syncthreads();
  if(t<32){
    float M=sm[0][t], S=ss[0][t];
    for(int q=1;q<8;q++){
      float mq=sm[q][t], sq_=ss[q][t];
      float mn=fmaxf(M,mq); S=S*__expf(M-mn)+sq_*__expf(mq-mn); M=mn;
    }
    ws[OFF_PM + (chunk*16+c)*32 + t]=M;
    ws[OFF_PS + (chunk*16+c)*32 + t]=S;
  }
}

__global__ __launch_bounds__(256) void k2b_merge(float* __restrict__ ws){
  int t = blockIdx.x*256 + threadIdx.x;
  if(t>=512) return;
  int c=t>>5, a=t&31;
  float M=-1e30f, S=0.f;
  for(int ch=0; ch<32; ch++){
    float mq=ws[OFF_PM+(ch*16+c)*32+a], sq_=ws[OFF_PS+(ch*16+c)*32+a];
    float mn=fmaxf(M,mq); S=S*__expf(M-mn)+sq_*__expf(mq-mn); M=mn;
  }
  ws[OFF_M + t]=M; ws[OFF_INV + t]=1.0f/S;
}

// ================= k3: s_global / v_global as MFMA GEMM, partials to scratch =================
// Output tile [d x a] per c: out[d][a] = sum_n sv[n][d] * w[n][a]
// Both operands split into bf16 hi+lo; 3 MFMAs per tile (hh + lh + hl) ~ fp32 grade.
// Each (c,chunk) block stores its partial tile to part[chunk][a*16+c][224] with
// float4 stores (no atomics); k4 sums the 64 chunks inline.
template<int NMT, bool ISV>
__device__ __forceinline__ void k3_body(const float* __restrict__ X, int dx0, int pb0,
    const float* __restrict__ L, float M0, float M1, float I0, float I1,
    int c, int nb0, int l15, int lq, float* __restrict__ partc){
  constexpr int XP = ISV ? 96 : 128;
  float4v acc[NMT][2];
  #pragma unroll
  for(int mi=0;mi<NMT;mi++){
    acc[mi][0]=(float4v){0.f,0.f,0.f,0.f};
    acc[mi][1]=(float4v){0.f,0.f,0.f,0.f};
  }
  #pragma unroll
  for(int kt=0;kt<4;kt++){
    int nb = nb0 + kt*32 + lq*8;
    // B fragments: w = expf(L - M) * INV, hi/lo split, cols a=l15 (nt0) and 16+l15 (nt1)
    short8 bh0, bl0, bh1, bl1;
    #pragma unroll
    for(int j=0;j<8;j++){
      long ro = ((long)(nb+j)*16 + c)*32;
      float w0 = __expf(L[ro + l15]      - M0) * I0;
      float w1 = __expf(L[ro + 16 + l15] - M1) * I1;
      short h_, lo_;
      split_bf(w0, h_, lo_); bh0[j]=h_; bl0[j]=lo_;
      split_bf(w1, h_, lo_); bh1[j]=h_; bl1[j]=lo_;
    }
    #pragma unroll
    for(int mi=0;mi<NMT;mi++){
      short8 ah, al_;
      #pragma unroll
      for(int j=0;j<8;j++){
        float f = X[((long)(nb+j)*16 + c)*XP + dx0 + mi*16 + l15];
        short h_, lo_;
        split_bf(f, h_, lo_); ah[j]=h_; al_[j]=lo_;
      }
      acc[mi][0]=__builtin_amdgcn_mfma_f32_16x16x32_bf16(ah,  bh0, acc[mi][0],0,0,0);
      acc[mi][0]=__builtin_amdgcn_mfma_f32_16x16x32_bf16(al_, bh0, acc[mi][0],0,0,0);
      acc[mi][0]=__builtin_amdgcn_mfma_f32_16x16x32_bf16(ah,  bl0, acc[mi][0],0,0,0);
      acc[mi][1]=__builtin_amdgcn_mfma_f32_16x16x32_bf16(ah,  bh1, acc[mi][1],0,0,0);
      acc[mi][1]=__builtin_amdgcn_mfma_f32_16x16x32_bf16(al_, bh1, acc[mi][1],0,0,0);
      acc[mi][1]=__builtin_amdgcn_mfma_f32_16x16x32_bf16(ah,  bl1, acc[mi][1],0,0,0);
    }
  }
  // epilogue: float4 store partials. C/D: row (d) = lq*4+reg, col (a) = l15
  #pragma unroll
  for(int mi=0;mi<NMT;mi++){
    #pragma unroll
    for(int nt=0;nt<2;nt++){
      int a = nt*16 + l15;
      long row = (long)(a*16 + c);
      float4 val = make_float4(acc[mi][nt][0], acc[mi][nt][1], acc[mi][nt][2], acc[mi][nt][3]);
      *(float4*)&partc[row*PART_ROWSZ + pb0 + mi*16 + lq*4] = val;
    }
  }
}

__global__ __launch_bounds__(256) void k3_globals(const float* __restrict__ s,
    const float* __restrict__ v, const float* __restrict__ ws, float* __restrict__ part){
  int c = blockIdx.x & 15; int chunk = blockIdx.x >> 4;   // 64 chunks of 128 nodes
  int t=threadIdx.x, wave=t>>6, lane=t&63;
  int l15=lane&15, lq=lane>>4;
  const float* L = ws + OFF_LOGITS;
  float M0 = ws[OFF_M   + c*32 + l15],      M1 = ws[OFF_M   + c*32 + 16 + l15];
  float I0 = ws[OFF_INV + c*32 + l15],      I1 = ws[OFF_INV + c*32 + 16 + l15];
  int nb0 = chunk*128;
  float* partc = part + (long)chunk*PART_CHUNKSZ;
  // m-tile split across waves: w0: s d 0..63, w1: s d 64..127, w2: v 0..47, w3: v 48..95
  if(wave==0)      k3_body<4,false>(s, 0,  0,   L, M0,M1,I0,I1, c, nb0, l15, lq, partc);
  else if(wave==1) k3_body<4,false>(s, 64, 64,  L, M0,M1,I0,I1, c, nb0, l15, lq, partc);
  else if(wave==2) k3_body<3,true >(v, 0,  128, L, M0,M1,I0,I1, c, nb0, l15, lq, partc);
  else             k3_body<3,true >(v, 48, 176, L, M0,M1,I0,I1, c, nb0, l15, lq, partc);
}

// ================= k4: k / val GVPs -> K_att / V_att bf16 fragment buffers =================
// 128 threads: wave0 handles p=0 (K), wave1 handles p=1 (V) concurrently.
// Wave0 additionally reduces the 64 chunk-partials; per-wave cat/vhb/sg buffers.
__global__ __launch_bounds__(128) void k4_kvgvp(float* __restrict__ wsf,
    const float* __restrict__ part,
    const float* __restrict__ k_wsb, const float* __restrict__ k_wsvb,
    const float* __restrict__ v_wsb, const float* __restrict__ v_wsvb){
  int a = blockIdx.x >> 4, c = blockIdx.x & 15;
  int t=threadIdx.x, p=t>>6, lane=t&63;
  __shared__ __align__(16) float catw[2][160];
  __shared__ __align__(16) float vb2[96];
  __shared__ float vhb[2][96];
  __shared__ __align__(16) float sg[2][128];
  const float* W = wsf + OFF_WF;
  ushort_t* katt = (ushort_t*)(wsf + OFF_KATT);
  ushort_t* vatt = (ushort_t*)(wsf + OFF_VATT);
  long row = (long)a*16 + c;
  if(p==0){
    // reduce 64 chunk-partials for this (a,c) row: d 0..223 by lanes 0..55 (x4)
    float4 accp = make_float4(0.f,0.f,0.f,0.f);
    if(lane<56){
      const float* pp = part + row*PART_ROWSZ + lane*4;
      #pragma unroll 8
      for(int ch=0; ch<64; ch++){
        float4 x = *(const float4*)(pp + (long)ch*PART_CHUNKSZ);
        accp.x+=x.x; accp.y+=x.y; accp.z+=x.z; accp.w+=x.w;
      }
    }
    if(lane<32)      *(float4*)&catw[0][lane*4]  = accp;
    else if(lane<56) *(float4*)&vb2[(lane-32)*4] = accp;
  }
  if(a==0){ // zero pad slots k=56..63 (K) and n2=56..63 (V), all r, once per (c,h)
    for(int idx=t; idx<1024; idx+=128){
      int h2=idx&3, kk=56+((idx>>2)&7), r=idx>>5;
      katt[katt_idx(c,h2,kk,r)]=0;
      vatt[vatt_idx(c,h2,r,kk)]=0;
    }
  }
  __syncthreads();
  if(p==1 && lane<32) *(float4*)&catw[1][lane*4] = *(const float4*)&catw[0][lane*4];
  const float* wht  = W + (p? WF_VWH  : WF_KWH);
  const float* wst  = W + (p? WF_VWS  : WF_KWS);
  const float* wvt  = W + (p? WF_VWV  : WF_KWV);
  const float* wsvt = W + (p? WF_VWSV : WF_KWSV);
  const float* bs   = p? v_wsb : k_wsb;
  const float* bsv  = p? v_wsvb : k_wsvb;
  float* cat = catw[p];
  float* vh  = vhb[p];
  float* sgp = sg[p];
  int h = lane&31, half = lane>>5;
  float d0=0.f,d1=0.f,d2=0.f;
  for(int i=half*16; i<half*16+16; i++){
    float w_=wht[i*32+h];
    d0+=vb2[3*i]*w_; d1+=vb2[3*i+1]*w_; d2+=vb2[3*i+2]*w_;
  }
  d0 += __shfl_xor(d0,32,64); d1 += __shfl_xor(d1,32,64); d2 += __shfl_xor(d2,32,64);
  if(lane<32){
    cat[128+h] = sqrtf(fmaxf(d0*d0+d1*d1+d2*d2, 1e-8f));
    vh[3*h]=d0; vh[3*h+1]=d1; vh[3*h+2]=d2;
  }
  __syncthreads();
  float a0=bs[lane], a1=bs[lane+64];
  for(int j=0;j<160;j+=4){
    float4 c4=*((float4*)&cat[j]);
    a0 += c4.x*wst[j*128+lane]      + c4.y*wst[(j+1)*128+lane]
        + c4.z*wst[(j+2)*128+lane]  + c4.w*wst[(j+3)*128+lane];
    a1 += c4.x*wst[j*128+64+lane]   + c4.y*wst[(j+1)*128+64+lane]
        + c4.z*wst[(j+2)*128+64+lane]+ c4.w*wst[(j+3)*128+64+lane];
  }
  float sig0=1.f/(1.f+__expf(-a0)), sig1=1.f/(1.f+__expf(-a1));
  float silu0=a0*sig0, silu1=a1*sig1;
  sgp[lane]=sig0; sgp[lane+64]=sig1;
  // store s-part
  {
    int o=lane, hh2=o>>5, k=o&31;
    if(p==0) katt[katt_idx(c,hh2,k,a)] = (ushort_t)f2bf(silu0);
    else     vatt[vatt_idx(c,hh2,a,k)] = (ushort_t)f2bf(silu0);
  }
  {
    int o=lane+64, hh2=o>>5, k=o&31;
    if(p==0) katt[katt_idx(c,hh2,k,a)] = (ushort_t)f2bf(silu1);
    else     vatt[vatt_idx(c,hh2,a,k)] = (ushort_t)f2bf(silu1);
  }
  __syncthreads();
  float gacc=0.f;
  for(int o=half*64; o<half*64+64; o+=4){
    float4 s4_=*((float4*)&sgp[o]);
    gacc += s4_.x*wsvt[o*32+h]+s4_.y*wsvt[(o+1)*32+h]+s4_.z*wsvt[(o+2)*32+h]+s4_.w*wsvt[(o+3)*32+h];
  }
  gacc += __shfl_xor(gacc,32,64);
  float sgate = 1.f/(1.f+__expf(-(gacc + bsv[h])));
  float e0=0.f,e1=0.f,e2=0.f;
  for(int hh=half*16; hh<half*16+16; hh++){
    float w_=wvt[hh*32+h];
    e0+=vh[3*hh]*w_; e1+=vh[3*hh+1]*w_; e2+=vh[3*hh+2]*w_;
  }
  e0+=__shfl_xor(e0,32,64); e1+=__shfl_xor(e1,32,64); e2+=__shfl_xor(e2,32,64);
  if(lane<32){
    int hh2=lane>>3, oo=lane&7;
    float vals[3]={e0*sgate, e1*sgate, e2*sgate};
    #pragma unroll
    for(int d=0;d<3;d++){
      if(p==0) katt[katt_idx(c,hh2,32+oo*3+d,a)] = (ushort_t)f2bf(vals[d]);
      else     vatt[vatt_idx(c,hh2,a,32+oo*3+d)] = (ushort_t)f2bf(vals[d]);
    }
  }
}

// ================= k5: MFMA attention (reads q_att from d_out, overwrites outputs) ===========
// NOTE: no __syncthreads — al slices are strictly per-wave.
__global__ __launch_bounds__(256) void k5_attn(const float* __restrict__ wsf, float* out){
  __shared__ ushort_t al[4][4*16*40];   // alpha bf16, per wave, per h rows padded to 40
  int t=threadIdx.x, wave=t>>6, lane=t&63;
  int l15=lane&15, lq=lane>>4;
  int c=blockIdx.y;
  long n0 = ((long)blockIdx.x*4+wave)*16;
  const ushort_t* qatt = (const ushort_t*)out;    // ALIASES out: all reads precede writes
  const short8* KA = (const short8*)(wsf + OFF_KATT);
  const short8* VA = (const short8*)(wsf + OFF_VATT);
  const float scale = 0.15811388300841897f;  // 1/sqrt(40)
  float4v e[4][2];
  #pragma unroll
  for(int h=0;h<4;h++){ e[h][0]=(float4v){0.f,0.f,0.f,0.f}; e[h][1]=e[h][0]; }
  #pragma unroll
  for(int h=0;h<4;h++){
    #pragma unroll
    for(int kt=0;kt<2;kt++){
      short8 a = *(const short8*)&qatt[(((n0+l15)*16 + c)*4 + h)*64 + kt*32 + lq*8];
      e[h][0]=__builtin_amdgcn_mfma_f32_16x16x32_bf16(a, KA[(((c*4+h)*2+kt)*2+0)*64+lane], e[h][0],0,0,0);
      e[h][1]=__builtin_amdgcn_mfma_f32_16x16x32_bf16(a, KA[(((c*4+h)*2+kt)*2+1)*64+lane], e[h][1],0,0,0);
    }
  }
  ushort_t* alw = al[wave];
  #pragma unroll
  for(int h=0;h<4;h++){
    #pragma unroll
    for(int reg=0;reg<4;reg++){
      float a0=e[h][0][reg]*scale, a1=e[h][1][reg]*scale;
      float m=fmaxf(a0,a1);
      m=fmaxf(m,__shfl_xor(m,1,64)); m=fmaxf(m,__shfl_xor(m,2,64));
      m=fmaxf(m,__shfl_xor(m,4,64)); m=fmaxf(m,__shfl_xor(m,8,64));
      float p0=__expf(a0-m), p1=__expf(a1-m);
      float sum=p0+p1;
      sum+=__shfl_xor(sum,1,64); sum+=__shfl_xor(sum,2,64);
      sum+=__shfl_xor(sum,4,64); sum+=__shfl_xor(sum,8,64);
      float inv=1.f/sum;
      int row=lq*4+reg;
      alw[h*640 + row*40 + l15]      = (ushort_t)f2bf(p0*inv);
      alw[h*640 + row*40 + 16 + l15] = (ushort_t)f2bf(p1*inv);
    }
  }
  float* outv = out + 16777216;
  #pragma unroll
  for(int h=0;h<4;h++){
    short8 a = *(const short8*)&alw[h*640 + l15*40 + lq*8];
    #pragma unroll
    for(int nt=0;nt<4;nt++){
      float4v o_=(float4v){0.f,0.f,0.f,0.f};
      o_=__builtin_amdgcn_mfma_f32_16x16x32_bf16(a, VA[((c*4+h)*4+nt)*64+lane], o_,0,0,0);
      #pragma unroll
      for(int reg=0;reg<4;reg++){
        int n2=nt*16+l15, row=lq*4+reg;
        long inst=(n0+row)*16+c;
        float val=o_[reg];
        if(n2<32)      out[inst*128 + h*32+n2]=val;
        else if(n2<56) outv[inst*96 + h*24 + n2-32]=val;
      }
    }
  }
}

extern "C" void kernel_launch(void* const* d_in, const int* in_sizes, int n_in,
                              void* d_out, int out_size, void* d_ws, size_t ws_size,
                              hipStream_t stream){
  (void)in_sizes; (void)n_in; (void)out_size; (void)ws_size;
  const float* s = (const float*)d_in[0];
  const float* v = (const float*)d_in[1];
  float* wsf = (float*)d_ws;
  float* out = (float*)d_out;
  ushort_t* qatt  = (ushort_t*)d_out;
  ushort_t* vh_s  = (ushort_t*)((char*)d_out + VH_B);
  ushort_t* avn_s = (ushort_t*)((char*)d_out + AVN_B);
  float* part = (float*)((char*)d_out + PART_B);
  k0_prep<<<13,256,0,stream>>>(
      (const float*)d_in[2],(const float*)d_in[3],
      (const float*)d_in[5],(const float*)d_in[6],(const float*)d_in[8],(const float*)d_in[9],
      (const float*)d_in[11],(const float*)d_in[12],(const float*)d_in[14],(const float*)d_in[15],
      (const float*)d_in[17],(const float*)d_in[18],(const float*)d_in[20],(const float*)d_in[21], wsf);
  kA_vn<<<1024,256,0,stream>>>(v, wsf, vh_s, avn_s);
  kB_gemm<<<2048,256,0,stream>>>(s, wsf, (const float*)d_in[7], (const float*)d_in[4],
                                 (const float*)d_in[10], qatt, vh_s, avn_s);
  k2a_stats<<<dim3(16,32),256,0,stream>>>(wsf);
  k2b_merge<<<2,256,0,stream>>>(wsf);
  k3_globals<<<1024,256,0,stream>>>(s, v, wsf, part);
  k4_kvgvp<<<512,128,0,stream>>>(wsf, part, (const float*)d_in[13], (const float*)d_in[16],
                                 (const float*)d_in[19], (const float*)d_in[22]);
  k5_attn<<<dim3(128,16),256,0,stream>>>(wsf, out);
}

// Round 6
// 498.155 us; speedup vs baseline: 1.1407x; 1.0118x over previous
//
#include <hip/hip_runtime.h>
#include <stdint.h>

typedef unsigned short ushort_t;
typedef __attribute__((ext_vector_type(8))) short short8;   // 8 x bf16 bits
typedef __attribute__((ext_vector_type(4))) float float4v;  // MFMA C/D frag

static constexpr int N_=8192, C_=16;

// ---- ws layout (float offsets) ----
static constexpr long OFF_LOGITS = 0;                      // fp32 [131072][32]
static constexpr long OFF_PM  = 4194304;                   // [32][16][32]
static constexpr long OFF_PS  = 4210688;
static constexpr long OFF_M   = 4227072;                   // [16][32]
static constexpr long OFF_INV = 4227584;
static constexpr long OFF_SGL = 4228096;                   // (unused; layout stability)
static constexpr long OFF_VGL = 4293632;                   // (unused)
static constexpr long OFF_KATT= 4342784;                   // bf16 [c][h][kt2][nt2][64][8]
static constexpr long OFF_VATT= 4408320;                   // bf16 [c][h][nt4][64][8]
static constexpr long OFF_WF  = 4473856;
// sub-offsets (floats) in OFF_WF region
static constexpr long WF_WHQ=0, WF_WHWP=1024, WF_KWH=2048, WF_KWS=3072, WF_KWV=23552,
  WF_KWSV=24576, WF_VWH=28672, WF_VWS=29696, WF_VWV=50176, WF_VWSV=51200,
  WF_B1=55296 /*bf16[6][10][64][8]*/, WF_BG=70656 /*bf16[4][2][64][8]*/,
  WF_BV=72704 /*bf16[2][64][8]*/;

// ---- d_out scratch byte offsets (all consumed before final outputs written) ----
static constexpr long VH_B   = 67108864;   // bf16 [131072*3][32]   (in out_v region, dead before k5)
static constexpr long AVN_B  = 92274688;   // bf16 [131072][64]     (in out_v region, dead before k5)
// k3 partials: fp32 [64][512][224] at VH_B (29.36 MB). vh_s/avn_s are dead by the
// time k3 runs (consumed by kB_gemm); k5's outv overwrites this region afterward.
static constexpr long PART_B = 67108864;
static constexpr long PART_ROWSZ = 224;            // floats per (a*16+c) row
static constexpr long PART_CHUNKSZ = 512*224;      // floats per chunk

__device__ __forceinline__ uint32_t f2bf(float f){
  uint32_t u = __float_as_uint(f);
  return (u + 0x7FFFu + ((u>>16)&1u)) >> 16;
}

// split fp32 into bf16 hi + bf16 lo (hi+lo represents f to ~2^-17 relative)
__device__ __forceinline__ void split_bf(float f, short& hi, short& lo){
  uint32_t u = __float_as_uint(f);
  uint32_t h = (u + 0x7FFFu + ((u>>16)&1u)) >> 16;
  hi = (short)h;
  float fh = __uint_as_float(h << 16);
  float r = f - fh;
  uint32_t u2 = __float_as_uint(r);
  lo = (short)((u2 + 0x7FFFu + ((u2>>16)&1u)) >> 16);
}

// B-fragment index helpers for mfma_f32_16x16x32_bf16:
// B[k][n] lives at lane = ((k&31)>>3)*16 + (n&15), j = k&7, tile nt = n>>4 (n in 0..31), kt = k>>5.
__device__ __forceinline__ long katt_idx(int c, int h, int k, int r){
  int kt=k>>5, kk=k&31, nt=r>>4;
  int lane=((kk>>3)<<4)|(r&15), j=kk&7;
  return ((((long)(c*4+h)*2+kt)*2+nt)*64+lane)*8+j;
}
__device__ __forceinline__ long vatt_idx(int c, int h, int r, int n2){
  int nt=n2>>4;
  int lane=((r>>3)<<4)|(n2&15), j=r&7;
  return (((long)(c*4+h)*4+nt)*64+lane)*8+j;
}

// ================= k0: weight prep (transposes + bf16 B-fragments) =================
__global__ void k0_prep(const float* __restrict__ wpwh, const float* __restrict__ wpws,
    const float* __restrict__ qwh, const float* __restrict__ qws, const float* __restrict__ qwv,
    const float* __restrict__ qwsv, const float* __restrict__ kwh, const float* __restrict__ kws,
    const float* __restrict__ kwv, const float* __restrict__ kwsv, const float* __restrict__ vwh,
    const float* __restrict__ vws, const float* __restrict__ vwv, const float* __restrict__ vwsv,
    float* __restrict__ wsf){
  int job=blockIdx.x, t=threadIdx.x;
  float* W = wsf + OFF_WF;
  auto tr=[&](const float* src, float* dst, int O, int J){
    for(int idx=t; idx<O*J; idx+=blockDim.x){int o=idx/J, j=idx-o*J; dst[j*O+o]=src[idx];}
  };
  switch(job){
    case 0: tr(qwh,  W+WF_WHQ, 32,32); break;
    case 1: tr(wpwh, W+WF_WHWP,32,32); break;
    case 2: tr(kwh,  W+WF_KWH, 32,32); break;
    case 3: tr(kws,  W+WF_KWS, 128,160); break;
    case 4: tr(kwv,  W+WF_KWV, 32,32); break;
    case 5: tr(kwsv, W+WF_KWSV,32,128); break;
    case 6: tr(vwh,  W+WF_VWH, 32,32); break;
    case 7: tr(vws,  W+WF_VWS, 128,160); break;
    case 8: tr(vwv,  W+WF_VWV, 32,32); break;
    case 9: tr(vwsv, W+WF_VWSV,32,128); break;
    case 10: { // B1[k 192][n 160]: k<128 -> s; 128..159 -> vn_q; 160..191 -> vn_wp
      ushort_t* dst=(ushort_t*)(W+WF_B1);
      for(int idx=t; idx<30720; idx+=blockDim.x){
        int j=idx&7, lane=(idx>>3)&63, tn=idx>>9, nt=tn%10, kt=tn/10;
        int k=kt*32+((lane>>4)<<3)+j, n=nt*16+(lane&15);
        float val;
        if(k<128)       val = (n<128)? qws[n*160+k]            : wpws[(n-128)*160+k];
        else if(k<160)  val = (n<128)? qws[n*160+k]            : 0.f;
        else            val = (n<128)? 0.f                     : wpws[(n-128)*160+(k-32)];
        dst[idx]=(ushort_t)f2bf(val);
      } } break;
    case 11: { // gate B: wsv^T [128][32]
      ushort_t* dst=(ushort_t*)(W+WF_BG);
      for(int idx=t; idx<4096; idx+=blockDim.x){
        int j=idx&7, lane=(idx>>3)&63, tn=idx>>9, nt=tn&1, kt=tn>>1;
        int k=kt*32+((lane>>4)<<3)+j, n=nt*16+(lane&15);
        dst[idx]=(ushort_t)f2bf(qwsv[n*128+k]);
      } } break;
    case 12: { // v_out B: wv^T [32][32]
      ushort_t* dst=(ushort_t*)(W+WF_BV);
      for(int idx=t; idx<1024; idx+=blockDim.x){
        int j=idx&7, lane=(idx>>3)&63, nt=idx>>9;
        int k=((lane>>4)<<3)+j, n=nt*16+(lane&15);
        dst[idx]=(ushort_t)f2bf(qwv[n*32+k]);
      } } break;
  }
}

// ================= kA: vh_q / vn_q / vn_wp (VALU, small) =================
__global__ __launch_bounds__(256) void kA_vn(const float* __restrict__ v,
    const float* __restrict__ wsf, ushort_t* __restrict__ vh_s, ushort_t* __restrict__ avn_s){
  __shared__ float whq[1024], whwp[1024];
  __shared__ float vb[4][96];
  int t=threadIdx.x, wave=t>>6, lane=t&63;
  for(int i=t;i<1024;i+=256){ whq[i]=wsf[OFF_WF+WF_WHQ+i]; whwp[i]=wsf[OFF_WF+WF_WHWP+i]; }
  __syncthreads();
  int h=lane&31, half=lane>>5;
  for(int it=0; it<32; it++){
    long inst = ((long)blockIdx.x*4 + wave)*32 + it;
    if(lane<48) ((float2*)vb[wave])[lane] = ((const float2*)v)[inst*48+lane];
    float d0=0,d1=0,d2=0;
    for(int i=half*16;i<half*16+16;i++){ float w=whq[i*32+h];
      d0+=vb[wave][3*i]*w; d1+=vb[wave][3*i+1]*w; d2+=vb[wave][3*i+2]*w; }
    d0+=__shfl_xor(d0,32,64); d1+=__shfl_xor(d1,32,64); d2+=__shfl_xor(d2,32,64);
    if(lane<32){
      float vn=sqrtf(fmaxf(d0*d0+d1*d1+d2*d2,1e-8f));
      avn_s[inst*64+h]=(ushort_t)f2bf(vn);
      vh_s[(inst*3+0)*32+h]=(ushort_t)f2bf(d0);
      vh_s[(inst*3+1)*32+h]=(ushort_t)f2bf(d1);
      vh_s[(inst*3+2)*32+h]=(ushort_t)f2bf(d2);
    }
    float e0=0,e1=0,e2=0;
    for(int i=half*16;i<half*16+16;i++){ float w=whwp[i*32+h];
      e0+=vb[wave][3*i]*w; e1+=vb[wave][3*i+1]*w; e2+=vb[wave][3*i+2]*w; }
    e0+=__shfl_xor(e0,32,64); e1+=__shfl_xor(e1,32,64); e2+=__shfl_xor(e2,32,64);
    if(lane<32){
      float vn=sqrtf(fmaxf(e0*e0+e1*e1+e2*e2,1e-8f));
      avn_s[inst*64+32+h]=(ushort_t)f2bf(vn);
    }
  }
}

// ================= kB: fused MFMA GEMM (q s_out + wp logits + gate + v_out) =================
// M=32 rows per wave (two 16-row tiles): halves per-output B-fragment traffic.
// All LDS slices per-wave; no barriers. Pads (cols 56..63) never touched (k5 masks).
__global__ __launch_bounds__(256) void kB_gemm(const float* __restrict__ s,
    float* __restrict__ wsf,
    const float* __restrict__ qwsb, const float* __restrict__ wpwsb,
    const float* __restrict__ qwsvb,
    ushort_t* __restrict__ qatt, const ushort_t* __restrict__ vh_s,
    const ushort_t* __restrict__ avn_s){
  __shared__ ushort_t sigl[4][16*136];   // sigmoid(s_out) bf16, per-wave slice (reused per half)
  __shared__ float    gsigl[4][16*33];   // sigmoid(gate) fp32, per-wave slice
  int t=threadIdx.x, wave=t>>6, lane=t&63;
  int l15=lane&15, lq=lane>>4;
  long m0 = ((long)blockIdx.x*4 + wave)*32;
  const short8* B1 = (const short8*)(wsf + OFF_WF + WF_B1);
  const short8* BG = (const short8*)(wsf + OFF_WF + WF_BG);
  const short8* BV = (const short8*)(wsf + OFF_WF + WF_BV);
  float4v acc[2][10];
  #pragma unroll
  for(int hf=0;hf<2;hf++)
    #pragma unroll
    for(int i=0;i<10;i++) acc[hf][i]=(float4v){0.f,0.f,0.f,0.f};
  // K 0..127: s (fp32 -> bf16 on the fly), both halves per B-fragment
  #pragma unroll
  for(int kt=0;kt<4;kt++){
    const float* sp0 = s + (m0+l15)*128    + kt*32 + lq*8;
    const float* sp1 = s + (m0+16+l15)*128 + kt*32 + lq*8;
    float4 f0=*(const float4*)sp0, f1=*(const float4*)(sp0+4);
    float4 g0_=*(const float4*)sp1, g1_=*(const float4*)(sp1+4);
    short8 a0, a1;
    a0[0]=(short)f2bf(f0.x); a0[1]=(short)f2bf(f0.y); a0[2]=(short)f2bf(f0.z); a0[3]=(short)f2bf(f0.w);
    a0[4]=(short)f2bf(f1.x); a0[5]=(short)f2bf(f1.y); a0[6]=(short)f2bf(f1.z); a0[7]=(short)f2bf(f1.w);
    a1[0]=(short)f2bf(g0_.x); a1[1]=(short)f2bf(g0_.y); a1[2]=(short)f2bf(g0_.z); a1[3]=(short)f2bf(g0_.w);
    a1[4]=(short)f2bf(g1_.x); a1[5]=(short)f2bf(g1_.y); a1[6]=(short)f2bf(g1_.z); a1[7]=(short)f2bf(g1_.w);
    #pragma unroll
    for(int nt=0;nt<10;nt++){
      short8 b = B1[(kt*10+nt)*64+lane];
      acc[0][nt]=__builtin_amdgcn_mfma_f32_16x16x32_bf16(a0, b, acc[0][nt],0,0,0);
      acc[1][nt]=__builtin_amdgcn_mfma_f32_16x16x32_bf16(a1, b, acc[1][nt],0,0,0);
    }
  }
  // K 128..191: [vn_q | vn_wp]
  #pragma unroll
  for(int kt=4;kt<6;kt++){
    short8 a0 = *(const short8*)&avn_s[(m0+l15)*64    + (kt-4)*32 + lq*8];
    short8 a1 = *(const short8*)&avn_s[(m0+16+l15)*64 + (kt-4)*32 + lq*8];
    #pragma unroll
    for(int nt=0;nt<10;nt++){
      short8 b = B1[(kt*10+nt)*64+lane];
      acc[0][nt]=__builtin_amdgcn_mfma_f32_16x16x32_bf16(a0, b, acc[0][nt],0,0,0);
      acc[1][nt]=__builtin_amdgcn_mfma_f32_16x16x32_bf16(a1, b, acc[1][nt],0,0,0);
    }
  }
  ushort_t* sl = sigl[wave]; float* gl = gsigl[wave];
  // ---- per-half epilogue (static unroll: rule #20) ----
  #pragma unroll
  for(int hf=0;hf<2;hf++){
    long mh = m0 + hf*16;
    // silu -> q_att (bf16), sigmoid -> LDS; logits -> ws (fp32)
    #pragma unroll
    for(int nt=0;nt<8;nt++){
      float b = qwsb[nt*16+l15];
      #pragma unroll
      for(int reg=0;reg<4;reg++){
        float x = acc[hf][nt][reg] + b;
        float sg = 1.f/(1.f+__expf(-x));
        int row = lq*4+reg, col=nt*16+l15;
        long inst = mh+row;
        qatt[(inst*4 + (col>>5))*64 + (col&31)] = (ushort_t)f2bf(x*sg);
        sl[row*136+col] = (ushort_t)f2bf(sg);
      }
    }
    #pragma unroll
    for(int nt=8;nt<10;nt++){
      float b = wpwsb[(nt-8)*16+l15];
      #pragma unroll
      for(int reg=0;reg<4;reg++){
        long inst=mh+lq*4+reg;
        wsf[OFF_LOGITS + inst*32 + (nt-8)*16+l15] = acc[hf][nt][reg]+b;
      }
    }
    // gate GEMM: sigmoid(s_out)[16x128] @ wsv^T[128x32]  (same-wave LDS)
    float4v g0=(float4v){0.f,0.f,0.f,0.f}, g1=g0;
    #pragma unroll
    for(int kt=0;kt<4;kt++){
      short8 a = *(const short8*)&sl[l15*136 + kt*32 + lq*8];
      g0=__builtin_amdgcn_mfma_f32_16x16x32_bf16(a, BG[(kt*2+0)*64+lane], g0,0,0,0);
      g1=__builtin_amdgcn_mfma_f32_16x16x32_bf16(a, BG[(kt*2+1)*64+lane], g1,0,0,0);
    }
    {
      float b0 = qwsvb[l15], b1 = qwsvb[16+l15];
      #pragma unroll
      for(int reg=0;reg<4;reg++){
        int row=lq*4+reg;
        gl[row*33 + l15]    = 1.f/(1.f+__expf(-(g0[reg]+b0)));
        gl[row*33 + 16+l15] = 1.f/(1.f+__expf(-(g1[reg]+b1)));
      }
    }
    // v_out GEMM: vh[(inst,d) x 32] @ wv^T[32x32], gated, -> q_att qv part (bf16)
    #pragma unroll
    for(int tt=0;tt<3;tt++){
      short8 a = *(const short8*)&vh_s[(mh*3 + tt*16 + l15)*32 + lq*8];
      float4v v0=(float4v){0.f,0.f,0.f,0.f}, v1=v0;
      v0=__builtin_amdgcn_mfma_f32_16x16x32_bf16(a, BV[0*64+lane], v0,0,0,0);
      v1=__builtin_amdgcn_mfma_f32_16x16x32_bf16(a, BV[1*64+lane], v1,0,0,0);
      #pragma unroll
      for(int nt2=0;nt2<2;nt2++){
        #pragma unroll
        for(int reg=0;reg<4;reg++){
          int lr = tt*16 + lq*4 + reg;
          int il = lr/3, d = lr - il*3;
          int o = nt2*16+l15;
          float val = (nt2? v1[reg] : v0[reg]) * gl[il*33+o];
          long inst = mh + il;
          qatt[(inst*4 + (o>>3))*64 + 32 + (o&7)*3 + d] = (ushort_t)f2bf(val);
        }
      }
    }
  }
}

// ================= k2a/k2b: softmax-over-N stats =================
__global__ __launch_bounds__(256) void k2a_stats(float* __restrict__ ws){
  int c = blockIdx.x; int chunk = blockIdx.y;
  int t=threadIdx.x; int i=t>>5, a=t&31;
  const float* L = ws + OFF_LOGITS;
  float m=-1e30f, sum=0.f;
  for(int k2=0;k2<32;k2++){
    int n = chunk*256 + k2*8 + i;
    float x = L[((long)n*16 + c)*32 + a];
    float mn = fmaxf(m,x);
    sum = sum*__expf(m-mn) + __expf(x-mn);
    m = mn;
  }
  __shared__ float sm[8][32], ss[8][32];
  sm[i][a]=m; ss[i][a]=sum;
  __syncthreads();
  if(t<32){
    float M=sm[0][t], S=ss[0][t];
    for(int q=1;q<8;q++){
      float mq=sm[q][t], sq_=ss[q][t];
      float mn=fmaxf(M,mq); S=S*__expf(M-mn)+sq_*__expf(mq-mn); M=mn;
    }
    ws[OFF_PM + (chunk*16+c)*32 + t]=M;
    ws[OFF_PS + (chunk*16+c)*32 + t]=S;
  }
}

__global__ __launch_bounds__(256) void k2b_merge(float* __restrict__ ws){
  int t = blockIdx.x*256 + threadIdx.x;
  if(t>=512) return;
  int c=t>>5, a=t&31;
  float M=-1e30f, S=0.f;
  for(int ch=0; ch<32; ch++){
    float mq=ws[OFF_PM+(ch*16+c)*32+a], sq_=ws[OFF_PS+(ch*16+c)*32+a];
    float mn=fmaxf(M,mq); S=S*__expf(M-mn)+sq_*__expf(mq-mn); M=mn;
  }
  ws[OFF_M + t]=M; ws[OFF_INV + t]=1.0f/S;
}

// ================= k3: s_global / v_global as MFMA GEMM, partials to scratch =================
// Output tile [d x a] per c: out[d][a] = sum_n sv[n][d] * w[n][a]
// Both operands split into bf16 hi+lo; 3 MFMAs per tile (hh + lh + hl) ~ fp32 grade.
// Each (c,chunk) block stores its partial tile to part[chunk][a*16+c][224] with
// float4 stores (no atomics); k4 sums the 64 chunks inline.
template<int NMT, bool ISV>
__device__ __forceinline__ void k3_body(const float* __restrict__ X, int dx0, int pb0,
    const float* __restrict__ L, float M0, float M1, float I0, float I1,
    int c, int nb0, int l15, int lq, float* __restrict__ partc){
  constexpr int XP = ISV ? 96 : 128;
  float4v acc[NMT][2];
  #pragma unroll
  for(int mi=0;mi<NMT;mi++){
    acc[mi][0]=(float4v){0.f,0.f,0.f,0.f};
    acc[mi][1]=(float4v){0.f,0.f,0.f,0.f};
  }
  #pragma unroll
  for(int kt=0;kt<4;kt++){
    int nb = nb0 + kt*32 + lq*8;
    // B fragments: w = expf(L - M) * INV, hi/lo split, cols a=l15 (nt0) and 16+l15 (nt1)
    short8 bh0, bl0, bh1, bl1;
    #pragma unroll
    for(int j=0;j<8;j++){
      long ro = ((long)(nb+j)*16 + c)*32;
      float w0 = __expf(L[ro + l15]      - M0) * I0;
      float w1 = __expf(L[ro + 16 + l15] - M1) * I1;
      short h_, lo_;
      split_bf(w0, h_, lo_); bh0[j]=h_; bl0[j]=lo_;
      split_bf(w1, h_, lo_); bh1[j]=h_; bl1[j]=lo_;
    }
    #pragma unroll
    for(int mi=0;mi<NMT;mi++){
      short8 ah, al_;
      #pragma unroll
      for(int j=0;j<8;j++){
        float f = X[((long)(nb+j)*16 + c)*XP + dx0 + mi*16 + l15];
        short h_, lo_;
        split_bf(f, h_, lo_); ah[j]=h_; al_[j]=lo_;
      }
      acc[mi][0]=__builtin_amdgcn_mfma_f32_16x16x32_bf16(ah,  bh0, acc[mi][0],0,0,0);
      acc[mi][0]=__builtin_amdgcn_mfma_f32_16x16x32_bf16(al_, bh0, acc[mi][0],0,0,0);
      acc[mi][0]=__builtin_amdgcn_mfma_f32_16x16x32_bf16(ah,  bl0, acc[mi][0],0,0,0);
      acc[mi][1]=__builtin_amdgcn_mfma_f32_16x16x32_bf16(ah,  bh1, acc[mi][1],0,0,0);
      acc[mi][1]=__builtin_amdgcn_mfma_f32_16x16x32_bf16(al_, bh1, acc[mi][1],0,0,0);
      acc[mi][1]=__builtin_amdgcn_mfma_f32_16x16x32_bf16(ah,  bl1, acc[mi][1],0,0,0);
    }
  }
  // epilogue: float4 store partials. C/D: row (d) = lq*4+reg, col (a) = l15
  #pragma unroll
  for(int mi=0;mi<NMT;mi++){
    #pragma unroll
    for(int nt=0;nt<2;nt++){
      int a = nt*16 + l15;
      long row = (long)(a*16 + c);
      float4 val = make_float4(acc[mi][nt][0], acc[mi][nt][1], acc[mi][nt][2], acc[mi][nt][3]);
      *(float4*)&partc[row*PART_ROWSZ + pb0 + mi*16 + lq*4] = val;
    }
  }
}

__global__ __launch_bounds__(256) void k3_globals(const float* __restrict__ s,
    const float* __restrict__ v, const float* __restrict__ ws, float* __restrict__ part){
  int c = blockIdx.x & 15; int chunk = blockIdx.x >> 4;   // 64 chunks of 128 nodes
  int t=threadIdx.x, wave=t>>6, lane=t&63;
  int l15=lane&15, lq=lane>>4;
  const float* L = ws + OFF_LOGITS;
  float M0 = ws[OFF_M   + c*32 + l15],      M1 = ws[OFF_M   + c*32 + 16 + l15];
  float I0 = ws[OFF_INV + c*32 + l15],      I1 = ws[OFF_INV + c*32 + 16 + l15];
  int nb0 = chunk*128;
  float* partc = part + (long)chunk*PART_CHUNKSZ;
  // m-tile split across waves: w0: s d 0..63, w1: s d 64..127, w2: v 0..47, w3: v 48..95
  if(wave==0)      k3_body<4,false>(s, 0,  0,   L, M0,M1,I0,I1, c, nb0, l15, lq, partc);
  else if(wave==1) k3_body<4,false>(s, 64, 64,  L, M0,M1,I0,I1, c, nb0, l15, lq, partc);
  else if(wave==2) k3_body<3,true >(v, 0,  128, L, M0,M1,I0,I1, c, nb0, l15, lq, partc);
  else             k3_body<3,true >(v, 48, 176, L, M0,M1,I0,I1, c, nb0, l15, lq, partc);
}

// ================= k4: k / val GVPs -> K_att / V_att bf16 fragment buffers =================
// 128 threads: wave0 handles p=0 (K), wave1 handles p=1 (V) concurrently.
// Wave0 additionally reduces the 64 chunk-partials; per-wave cat/vhb/sg buffers.
__global__ __launch_bounds__(128) void k4_kvgvp(float* __restrict__ wsf,
    const float* __restrict__ part,
    const float* __restrict__ k_wsb, const float* __restrict__ k_wsvb,
    const float* __restrict__ v_wsb, const float* __restrict__ v_wsvb){
  int a = blockIdx.x >> 4, c = blockIdx.x & 15;
  int t=threadIdx.x, p=t>>6, lane=t&63;
  __shared__ __align__(16) float catw[2][160];
  __shared__ __align__(16) float vb2[96];
  __shared__ float vhb[2][96];
  __shared__ __align__(16) float sg[2][128];
  const float* W = wsf + OFF_WF;
  ushort_t* katt = (ushort_t*)(wsf + OFF_KATT);
  ushort_t* vatt = (ushort_t*)(wsf + OFF_VATT);
  long row = (long)a*16 + c;
  if(p==0){
    // reduce 64 chunk-partials for this (a,c) row: d 0..223 by lanes 0..55 (x4)
    float4 accp = make_float4(0.f,0.f,0.f,0.f);
    if(lane<56){
      const float* pp = part + row*PART_ROWSZ + lane*4;
      #pragma unroll 8
      for(int ch=0; ch<64; ch++){
        float4 x = *(const float4*)(pp + (long)ch*PART_CHUNKSZ);
        accp.x+=x.x; accp.y+=x.y; accp.z+=x.z; accp.w+=x.w;
      }
    }
    if(lane<32)      *(float4*)&catw[0][lane*4]  = accp;
    else if(lane<56) *(float4*)&vb2[(lane-32)*4] = accp;
  }
  if(a==0){ // zero pad slots k=56..63 (K) and n2=56..63 (V), all r, once per (c,h)
    for(int idx=t; idx<1024; idx+=128){
      int h2=idx&3, kk=56+((idx>>2)&7), r=idx>>5;
      katt[katt_idx(c,h2,kk,r)]=0;
      vatt[vatt_idx(c,h2,r,kk)]=0;
    }
  }
  __syncthreads();
  if(p==1 && lane<32) *(float4*)&catw[1][lane*4] = *(const float4*)&catw[0][lane*4];
  const float* wht  = W + (p? WF_VWH  : WF_KWH);
  const float* wst  = W + (p? WF_VWS  : WF_KWS);
  const float* wvt  = W + (p? WF_VWV  : WF_KWV);
  const float* wsvt = W + (p? WF_VWSV : WF_KWSV);
  const float* bs   = p? v_wsb : k_wsb;
  const float* bsv  = p? v_wsvb : k_wsvb;
  float* cat = catw[p];
  float* vh  = vhb[p];
  float* sgp = sg[p];
  int h = lane&31, half = lane>>5;
  float d0=0.f,d1=0.f,d2=0.f;
  for(int i=half*16; i<half*16+16; i++){
    float w_=wht[i*32+h];
    d0+=vb2[3*i]*w_; d1+=vb2[3*i+1]*w_; d2+=vb2[3*i+2]*w_;
  }
  d0 += __shfl_xor(d0,32,64); d1 += __shfl_xor(d1,32,64); d2 += __shfl_xor(d2,32,64);
  if(lane<32){
    cat[128+h] = sqrtf(fmaxf(d0*d0+d1*d1+d2*d2, 1e-8f));
    vh[3*h]=d0; vh[3*h+1]=d1; vh[3*h+2]=d2;
  }
  __syncthreads();
  float a0=bs[lane], a1=bs[lane+64];
  for(int j=0;j<160;j+=4){
    float4 c4=*((float4*)&cat[j]);
    a0 += c4.x*wst[j*128+lane]      + c4.y*wst[(j+1)*128+lane]
        + c4.z*wst[(j+2)*128+lane]  + c4.w*wst[(j+3)*128+lane];
    a1 += c4.x*wst[j*128+64+lane]   + c4.y*wst[(j+1)*128+64+lane]
        + c4.z*wst[(j+2)*128+64+lane]+ c4.w*wst[(j+3)*128+64+lane];
  }
  float sig0=1.f/(1.f+__expf(-a0)), sig1=1.f/(1.f+__expf(-a1));
  float silu0=a0*sig0, silu1=a1*sig1;
  sgp[lane]=sig0; sgp[lane+64]=sig1;
  // store s-part
  {
    int o=lane, hh2=o>>5, k=o&31;
    if(p==0) katt[katt_idx(c,hh2,k,a)] = (ushort_t)f2bf(silu0);
    else     vatt[vatt_idx(c,hh2,a,k)] = (ushort_t)f2bf(silu0);
  }
  {
    int o=lane+64, hh2=o>>5, k=o&31;
    if(p==0) katt[katt_idx(c,hh2,k,a)] = (ushort_t)f2bf(silu1);
    else     vatt[vatt_idx(c,hh2,a,k)] = (ushort_t)f2bf(silu1);
  }
  __syncthreads();
  float gacc=0.f;
  for(int o=half*64; o<half*64+64; o+=4){
    float4 s4_=*((float4*)&sgp[o]);
    gacc += s4_.x*wsvt[o*32+h]+s4_.y*wsvt[(o+1)*32+h]+s4_.z*wsvt[(o+2)*32+h]+s4_.w*wsvt[(o+3)*32+h];
  }
  gacc += __shfl_xor(gacc,32,64);
  float sgate = 1.f/(1.f+__expf(-(gacc + bsv[h])));
  float e0=0.f,e1=0.f,e2=0.f;
  for(int hh=half*16; hh<half*16+16; hh++){
    float w_=wvt[hh*32+h];
    e0+=vh[3*hh]*w_; e1+=vh[3*hh+1]*w_; e2+=vh[3*hh+2]*w_;
  }
  e0+=__shfl_xor(e0,32,64); e1+=__shfl_xor(e1,32,64); e2+=__shfl_xor(e2,32,64);
  if(lane<32){
    int hh2=lane>>3, oo=lane&7;
    float vals[3]={e0*sgate, e1*sgate, e2*sgate};
    #pragma unroll
    for(int d=0;d<3;d++){
      if(p==0) katt[katt_idx(c,hh2,32+oo*3+d,a)] = (ushort_t)f2bf(vals[d]);
      else     vatt[vatt_idx(c,hh2,a,32+oo*3+d)] = (ushort_t)f2bf(vals[d]);
    }
  }
}

// ================= k5: MFMA attention (reads q_att from d_out, overwrites outputs) ===========
// NOTE: no __syncthreads — al slices are strictly per-wave.
// Pad cols 56..63 of qatt are NEVER written by kB; masked to zero here in registers.
__global__ __launch_bounds__(256) void k5_attn(const float* __restrict__ wsf, float* out){
  __shared__ ushort_t al[4][4*16*40];   // alpha bf16, per wave, per h rows padded to 40
  int t=threadIdx.x, wave=t>>6, lane=t&63;
  int l15=lane&15, lq=lane>>4;
  int c=blockIdx.y;
  long n0 = ((long)blockIdx.x*4+wave)*16;
  const ushort_t* qatt = (const ushort_t*)out;    // ALIASES out: all reads precede writes
  const short8* KA = (const short8*)(wsf + OFF_KATT);
  const short8* VA = (const short8*)(wsf + OFF_VATT);
  const float scale = 0.15811388300841897f;  // 1/sqrt(40)
  const short8 zero8 = {0,0,0,0,0,0,0,0};
  float4v e[4][2];
  #pragma unroll
  for(int h=0;h<4;h++){ e[h][0]=(float4v){0.f,0.f,0.f,0.f}; e[h][1]=e[h][0]; }
  #pragma unroll
  for(int h=0;h<4;h++){
    #pragma unroll
    for(int kt=0;kt<2;kt++){
      short8 a = *(const short8*)&qatt[(((n0+l15)*16 + c)*4 + h)*64 + kt*32 + lq*8];
      if(kt==1 && lq==3) a = zero8;   // pad cols 56..63: mask stale memory (KA rows also 0)
      e[h][0]=__builtin_amdgcn_mfma_f32_16x16x32_bf16(a, KA[(((c*4+h)*2+kt)*2+0)*64+lane], e[h][0],0,0,0);
      e[h][1]=__builtin_amdgcn_mfma_f32_16x16x32_bf16(a, KA[(((c*4+h)*2+kt)*2+1)*64+lane], e[h][1],0,0,0);
    }
  }
  ushort_t* alw = al[wave];
  #pragma unroll
  for(int h=0;h<4;h++){
    #pragma unroll
    for(int reg=0;reg<4;reg++){
      float a0=e[h][0][reg]*scale, a1=e[h][1][reg]*scale;
      float m=fmaxf(a0,a1);
      m=fmaxf(m,__shfl_xor(m,1,64)); m=fmaxf(m,__shfl_xor(m,2,64));
      m=fmaxf(m,__shfl_xor(m,4,64)); m=fmaxf(m,__shfl_xor(m,8,64));
      float p0=__expf(a0-m), p1=__expf(a1-m);
      float sum=p0+p1;
      sum+=__shfl_xor(sum,1,64); sum+=__shfl_xor(sum,2,64);
      sum+=__shfl_xor(sum,4,64); sum+=__shfl_xor(sum,8,64);
      float inv=1.f/sum;
      int row=lq*4+reg;
      alw[h*640 + row*40 + l15]      = (ushort_t)f2bf(p0*inv);
      alw[h*640 + row*40 + 16 + l15] = (ushort_t)f2bf(p1*inv);
    }
  }
  float* outv = out + 16777216;
  #pragma unroll
  for(int h=0;h<4;h++){
    short8 a = *(const short8*)&alw[h*640 + l15*40 + lq*8];
    #pragma unroll
    for(int nt=0;nt<4;nt++){
      float4v o_=(float4v){0.f,0.f,0.f,0.f};
      o_=__builtin_amdgcn_mfma_f32_16x16x32_bf16(a, VA[((c*4+h)*4+nt)*64+lane], o_,0,0,0);
      #pragma unroll
      for(int reg=0;reg<4;reg++){
        int n2=nt*16+l15, row=lq*4+reg;
        long inst=(n0+row)*16+c;
        float val=o_[reg];
        if(n2<32)      out[inst*128 + h*32+n2]=val;
        else if(n2<56) outv[inst*96 + h*24 + n2-32]=val;
      }
    }
  }
}

extern "C" void kernel_launch(void* const* d_in, const int* in_sizes, int n_in,
                              void* d_out, int out_size, void* d_ws, size_t ws_size,
                              hipStream_t stream){
  (void)in_sizes; (void)n_in; (void)out_size; (void)ws_size;
  const float* s = (const float*)d_in[0];
  const float* v = (const float*)d_in[1];
  float* wsf = (float*)d_ws;
  float* out = (float*)d_out;
  ushort_t* qatt  = (ushort_t*)d_out;
  ushort_t* vh_s  = (ushort_t*)((char*)d_out + VH_B);
  ushort_t* avn_s = (ushort_t*)((char*)d_out + AVN_B);
  float* part = (float*)((char*)d_out + PART_B);
  k0_prep<<<13,256,0,stream>>>(
      (const float*)d_in[2],(const float*)d_in[3],
      (const float*)d_in[5],(const float*)d_in[6],(const float*)d_in[8],(const float*)d_in[9],
      (const float*)d_in[11],(const float*)d_in[12],(const float*)d_in[14],(const float*)d_in[15],
      (const float*)d_in[17],(const float*)d_in[18],(const float*)d_in[20],(const float*)d_in[21], wsf);
  kA_vn<<<1024,256,0,stream>>>(v, wsf, vh_s, avn_s);
  kB_gemm<<<1024,256,0,stream>>>(s, wsf, (const float*)d_in[7], (const float*)d_in[4],
                                 (const float*)d_in[10], qatt, vh_s, avn_s);
  k2a_stats<<<dim3(16,32),256,0,stream>>>(wsf);
  k2b_merge<<<2,256,0,stream>>>(wsf);
  k3_globals<<<1024,256,0,stream>>>(s, v, wsf, part);
  k4_kvgvp<<<512,128,0,stream>>>(wsf, part, (const float*)d_in[13], (const float*)d_in[16],
                                 (const float*)d_in[19], (const float*)d_in[22]);
  k5_attn<<<dim3(128,16),256,0,stream>>>(wsf, out);
}